// Round 5
// baseline (891.546 us; speedup 1.0000x reference)
//
#include <hip/hip_runtime.h>
#include <math.h>

#define N_NODES 100000
#define N_EDGES 1600000
#define HID     128
#define NGRAPH  256
#define GB      ((N_NODES + 63) / 64)               // 1563 gemm blocks per branch
#define GAT_NB  (N_NODES / 4)                       // 25000 gather blocks per branch
#define FGG_NB  (N_NODES / 16)                      // 6250 fused gather+gemm blocks per branch
#define PB      ((N_NODES + 63) / 64)               // 1563 pool blocks per branch
#define NBUCK   ((N_NODES + 511) / 512)             // 196 buckets (512 nodes each)
#define AVPT    16
#define ABLK    ((N_EDGES + 256 * AVPT - 1) / (256 * AVPT))  // 391 edge-sweep blocks per branch

typedef unsigned short u16;
typedef unsigned int   u32;
typedef __attribute__((ext_vector_type(8))) short    bf16x8;
typedef __attribute__((ext_vector_type(4))) float    f32x4;
typedef __attribute__((ext_vector_type(8))) unsigned short u16x8;

__device__ inline float b2f(u16 u) {
    union { unsigned int i; float f; } x; x.i = ((unsigned int)u) << 16; return x.f;
}
__device__ inline u16 f2b(float f) {
    union { float f; unsigned int i; } x; x.f = f;
    unsigned int r = x.i + 0x7fff + ((x.i >> 16) & 1);   // round-to-nearest-even
    return (u16)(r >> 16);
}

// ============================= CSR build (bucket-first, no per-node global atomics) =============================

__global__ __launch_bounds__(256) void bucket_count_kernel(
        const int* __restrict__ sc_ei, const int* __restrict__ fc_ei,
        int* __restrict__ bktcnt) {
    int b = blockIdx.x;
    int branch = b >= ABLK;
    int blk = branch ? b - ABLK : b;
    const int* dsts = (branch ? fc_ei : sc_ei) + N_EDGES;
    int* bc = bktcnt + (branch ? NBUCK : 0);
    __shared__ int hist[NBUCK];
    int tid = threadIdx.x;
    for (int i = tid; i < NBUCK; i += 256) hist[i] = 0;
    __syncthreads();
    int e0 = blk * (256 * AVPT) + tid;
    for (int k = 0; k < AVPT; ++k) {
        int e = e0 + k * 256;
        if (e < N_EDGES) atomicAdd(&hist[dsts[e] >> 9], 1);
    }
    __syncthreads();
    for (int i = tid; i < NBUCK; i += 256)
        if (hist[i]) atomicAdd(&bc[i], hist[i]);
}

__global__ __launch_bounds__(256) void bucket_scan_kernel(
        const int* __restrict__ bktcnt, int* __restrict__ bktoff, int* __restrict__ bcur) {
    __shared__ int lds[2][256];
    int tid = threadIdx.x;
    int v0 = (tid < NBUCK) ? bktcnt[tid] : 0;
    int v1 = (tid < NBUCK) ? bktcnt[NBUCK + tid] : 0;
    lds[0][tid] = v0;
    lds[1][tid] = v1;
    __syncthreads();
    for (int off = 1; off < 256; off <<= 1) {
        int t0 = (tid >= off) ? lds[0][tid - off] : 0;
        int t1 = (tid >= off) ? lds[1][tid - off] : 0;
        __syncthreads();
        lds[0][tid] += t0;
        lds[1][tid] += t1;
        __syncthreads();
    }
    if (tid < NBUCK) {
        int e0 = lds[0][tid] - v0;   // exclusive
        int e1 = lds[1][tid] - v1;
        bktoff[tid] = e0;
        bktoff[(NBUCK + 1) + tid] = e1;
        bcur[tid] = e0;
        bcur[NBUCK + tid] = e1;
    }
    if (tid == 0) {
        bktoff[NBUCK] = N_EDGES;
        bktoff[(NBUCK + 1) + NBUCK] = N_EDGES;
    }
}

__global__ __launch_bounds__(256) void buildA_kernel(
        const int* __restrict__ sc_ei, const int* __restrict__ fc_ei,
        int* __restrict__ bcur,
        u32* __restrict__ tmp_sc, u32* __restrict__ tmp_fc) {
    int b = blockIdx.x;
    int branch = b >= ABLK;
    int blk = branch ? b - ABLK : b;
    const int* ei = branch ? fc_ei : sc_ei;
    u32* tmp      = branch ? tmp_fc : tmp_sc;
    int* bc       = bcur + (branch ? NBUCK : 0);

    __shared__ int hist[NBUCK];
    __shared__ int cur[NBUCK];
    int tid = threadIdx.x;
    for (int i = tid; i < NBUCK; i += 256) hist[i] = 0;
    __syncthreads();

    int e0 = blk * (256 * AVPT) + tid;
    for (int k = 0; k < AVPT; ++k) {
        int e = e0 + k * 256;
        if (e < N_EDGES) atomicAdd(&hist[ei[N_EDGES + e] >> 9], 1);
    }
    __syncthreads();
    for (int i = tid; i < NBUCK; i += 256) {
        int c = hist[i];
        cur[i] = c ? atomicAdd(&bc[i], c) : 0;
    }
    __syncthreads();
    for (int k = 0; k < AVPT; ++k) {
        int e = e0 + k * 256;
        if (e < N_EDGES) {
            int s = ei[e], d = ei[N_EDGES + e];
            int pos = atomicAdd(&cur[d >> 9], 1);   // LDS cursor holds global slot
            tmp[pos] = ((u32)s << 9) | (u32)(d & 511);
        }
    }
}

__global__ __launch_bounds__(256) void bucket_fin_kernel(
        const u32* __restrict__ tmp_sc, const u32* __restrict__ tmp_fc,
        const int* __restrict__ bktoff,
        int* __restrict__ off_sc, int* __restrict__ off_fc,
        float* __restrict__ d_sc, float* __restrict__ d_fc,
        int* __restrict__ srcs_sc, int* __restrict__ srcs_fc) {
    int b = blockIdx.x;
    int branch = b >= NBUCK;
    int bucket = branch ? b - NBUCK : b;
    const u32* tmp = branch ? tmp_fc : tmp_sc;
    const int* bo  = bktoff + (branch ? (NBUCK + 1) : 0);
    int* off   = branch ? off_fc : off_sc;
    float* dis = branch ? d_fc : d_sc;
    int* srcs  = branch ? srcs_fc : srcs_sc;
    int node0 = bucket << 9;
    int beg = bo[bucket], end = bo[bucket + 1];

    __shared__ int cnt[512];
    __shared__ int cur[512];
    __shared__ int psum[256];
    int tid = threadIdx.x;
    cnt[2 * tid] = 0; cnt[2 * tid + 1] = 0;
    __syncthreads();
    for (int r = beg + tid; r < end; r += 256)
        atomicAdd(&cnt[tmp[r] & 511], 1);
    __syncthreads();
    int c0 = cnt[2 * tid], c1 = cnt[2 * tid + 1];
    int s = c0 + c1;
    psum[tid] = s;
    __syncthreads();
    for (int o = 1; o < 256; o <<= 1) {
        int t = (tid >= o) ? psum[tid - o] : 0;
        __syncthreads();
        psum[tid] += t;
        __syncthreads();
    }
    int base = beg + psum[tid] - s;   // exclusive start of node 2*tid
    int n0 = node0 + 2 * tid, n1 = node0 + 2 * tid + 1;
    if (n0 < N_NODES) { off[n0] = base;      dis[n0] = rsqrtf((float)c0 + 1.0f); }
    if (n1 < N_NODES) { off[n1] = base + c0; dis[n1] = rsqrtf((float)c1 + 1.0f); }
    cur[2 * tid] = base;
    cur[2 * tid + 1] = base + c0;
    __syncthreads();
    for (int r = beg + tid; r < end; r += 256) {
        u32 rec = tmp[r];
        int pos = atomicAdd(&cur[rec & 511], 1);
        srcs[pos] = rec >> 9;
    }
    if (b == 0 && tid == 0) { off_sc[N_NODES] = N_EDGES; off_fc[N_NODES] = N_EDGES; }
}

// ---- pre-convert+transpose weights: Wt[l'][n][k] = W[l][k][n] (bf16), l' = branch*3+l ----
__global__ void convert_w_kernel(const float* __restrict__ sc_W, const float* __restrict__ fc_W,
                                 u16* __restrict__ Wt) {
    int idx = blockIdx.x * 256 + threadIdx.x;  // 6*16384 total
    if (idx >= 6 * 16384) return;
    int lp = idx >> 14;
    int r = idx & 16383;
    int n = r >> 7, k = r & 127;
    const float* W = (lp >= 3) ? fc_W : sc_W;
    int l = (lp >= 3) ? lp - 3 : lp;
    Wt[idx] = f2b(W[(size_t)l * 16384 + k * 128 + n]);
}

// ============================= MFMA GEMM (layer 0 only: fp32 input, LDS-staged) =============================
__global__ __launch_bounds__(256) void gemm2_kernel(
        const void* __restrict__ A_sc, const void* __restrict__ A_fc, int a_fp32,
        const u16* __restrict__ Wt, int layer,
        const float* __restrict__ d_sc, const float* __restrict__ d_fc,
        u16* __restrict__ H_sc, u16* __restrict__ H_fc) {
    int branch = blockIdx.x >= GB;
    int blk = branch ? blockIdx.x - GB : blockIdx.x;
    const void* A = branch ? A_fc : A_sc;
    const float* dis = branch ? d_fc : d_sc;
    u16* H = branch ? H_fc : H_sc;
    const u16* W = Wt + (((size_t)branch * 3 + layer) << 14);

    __shared__ u16 Alds[64 * 136];   // rows padded to 136 u16 (272 B)
    __shared__ u16 Wlds[128 * 136];  // Wt rows: n-major, k contiguous
    const int tid = threadIdx.x;
    const int row0 = blk * 64;

    if (a_fp32) {
        const float* Af = (const float*)A;
#pragma unroll
        for (int i = 0; i < 8; ++i) {
            int idx = tid + i * 256;
            int r = idx >> 5, f = idx & 31;
            int grow = row0 + r;
            float4 v = (grow < N_NODES) ? *(const float4*)&Af[(size_t)grow * 128 + f * 4]
                                        : make_float4(0.f, 0.f, 0.f, 0.f);
            ushort4 o;
            o.x = f2b(v.x); o.y = f2b(v.y); o.z = f2b(v.z); o.w = f2b(v.w);
            *(ushort4*)&Alds[r * 136 + f * 4] = o;
        }
    } else {
        const u16* Ab = (const u16*)A;
#pragma unroll
        for (int i = 0; i < 4; ++i) {
            int idx = tid + i * 256;
            int r = idx >> 4, f = idx & 15;
            int grow = row0 + r;
            u16x8 v = {};
            if (grow < N_NODES) v = *(const u16x8*)&Ab[(size_t)grow * 128 + f * 8];
            *(u16x8*)&Alds[r * 136 + f * 8] = v;
        }
    }
#pragma unroll
    for (int i = 0; i < 8; ++i) {
        int idx = tid + i * 256;
        int n = idx >> 4, f = idx & 15;
        *(u16x8*)&Wlds[n * 136 + f * 8] = *(const u16x8*)&W[n * 128 + f * 8];
    }
    __syncthreads();

    const int wv = tid >> 6;
    const int lane = tid & 63;
    const int m = lane & 15;       // row (A) / col (B) within 16-tile
    const int quad = lane >> 4;    // k-subchunk

    bf16x8 af[4];
#pragma unroll
    for (int kt = 0; kt < 4; ++kt)
        af[kt] = *(const bf16x8*)&Alds[(wv * 16 + m) * 136 + kt * 32 + quad * 8];

    f32x4 acc[8];
#pragma unroll
    for (int ct = 0; ct < 8; ++ct) { acc[ct][0] = 0.f; acc[ct][1] = 0.f; acc[ct][2] = 0.f; acc[ct][3] = 0.f; }

#pragma unroll
    for (int ct = 0; ct < 8; ++ct) {
#pragma unroll
        for (int kt = 0; kt < 4; ++kt) {
            bf16x8 bf = *(const bf16x8*)&Wlds[(ct * 16 + m) * 136 + kt * 32 + quad * 8];
            acc[ct] = __builtin_amdgcn_mfma_f32_16x16x32_bf16(af[kt], bf, acc[ct], 0, 0, 0);
        }
    }

    float4 dv = *(const float4*)&dis[row0 + wv * 16 + quad * 4];  // ws-padded, OOB-safe
#pragma unroll
    for (int ct = 0; ct < 8; ++ct) {
        acc[ct][0] *= dv.x; acc[ct][1] *= dv.y; acc[ct][2] *= dv.z; acc[ct][3] *= dv.w;
    }

#pragma unroll
    for (int ct = 0; ct < 8; ++ct)
#pragma unroll
        for (int r = 0; r < 4; ++r)
            Alds[(wv * 16 + quad * 4 + r) * 136 + ct * 16 + m] = f2b(acc[ct][r]);
    __syncthreads();
#pragma unroll
    for (int i = 0; i < 4; ++i) {
        int idx = i * 64 + lane;
        int r = idx >> 4, f = idx & 15;
        int grow = row0 + wv * 16 + r;
        if (grow < N_NODES)
            *(u16x8*)&H[(size_t)grow * 128 + f * 8] = *(const u16x8*)&Alds[(wv * 16 + r) * 136 + f * 8];
    }
}

// ============================= fused gather(l) + gemm(l+1), v2 =============================
// r4 finding: 4-sequential-nodes-per-wave + barrier cut the fetch-issue rate
// (hbm 3.91->3.37 TB/s). v2 restores gather2's schedule: 1024-thread blocks,
// 16 waves, ONE node per wave (identical inner loop to gather2), one barrier,
// then waves 0-7 run the 16x128 MFMA tile (one 16-col slab each; W direct
// from global, L2-hot). 2 blocks/CU = 32 waves = full occupancy (VGPR<=64).
// Numerics identical to split pipeline.
__global__ __launch_bounds__(1024, 2) void fgg_kernel(
        const u16* __restrict__ h_sc_in, const u16* __restrict__ h_fc_in,
        const int* __restrict__ srcs_sc, const int* __restrict__ srcs_fc,
        const int* __restrict__ off_sc, const int* __restrict__ off_fc,
        const float* __restrict__ d_sc, const float* __restrict__ d_fc,
        const float* __restrict__ b_sc, const float* __restrict__ b_fc,  // bias of layer l
        const u16* __restrict__ Wt, int wl,                               // weight layer l+1
        u16* __restrict__ h_sc_out, u16* __restrict__ h_fc_out) {
    int bb = blockIdx.x;
    int branch = bb >= FGG_NB;
    if (branch) bb -= FGG_NB;
    const u16* h    = branch ? h_fc_in : h_sc_in;
    const int* srcs = branch ? srcs_fc : srcs_sc;
    const int* offs = branch ? off_fc : off_sc;
    const float* dis = branch ? d_fc : d_sc;
    const float* bias = branch ? b_fc : b_sc;
    u16* hout = branch ? h_fc_out : h_sc_out;
    const u16* W = Wt + (((size_t)branch * 3 + wl) << 14);

    __shared__ u16 xt[16 * 136];   // x tile; reused as epilogue transpose buffer

    const int tid = threadIdx.x;
    const int wv = tid >> 6;       // 0..15: one node per wave
    const int lane = tid & 63;
    const int quarter = lane >> 4;
    const int c = (lane & 15) * 8;
    const int node0 = bb * 16;     // N_NODES = 6250*16 exactly -> no OOB

    // ---- gather phase: one node per wave (gather2-identical schedule) ----
    {
        int node = node0 + wv;
        int beg = offs[node], end = offs[node + 1];
        u16x8 hv = *(const u16x8*)&h[(size_t)node * 128 + c];
        float dn = dis[node];
        float acc[8] = {0.f, 0.f, 0.f, 0.f, 0.f, 0.f, 0.f, 0.f};
        for (int j = beg + quarter; j < end; j += 16) {
            int o1 = (j + 4  < end) ? 4  : 0;
            int o2 = (j + 8  < end) ? 8  : 0;
            int o3 = (j + 12 < end) ? 12 : 0;
            float m1 = o1 ? 1.f : 0.f;
            float m2 = o2 ? 1.f : 0.f;
            float m3 = o3 ? 1.f : 0.f;
            int s0 = __builtin_nontemporal_load(&srcs[j]);
            int s1 = __builtin_nontemporal_load(&srcs[j + o1]);
            int s2 = __builtin_nontemporal_load(&srcs[j + o2]);
            int s3 = __builtin_nontemporal_load(&srcs[j + o3]);
            u16x8 v0 = *(const u16x8*)&h[(size_t)s0 * 128 + c];
            u16x8 v1 = *(const u16x8*)&h[(size_t)s1 * 128 + c];
            u16x8 v2 = *(const u16x8*)&h[(size_t)s2 * 128 + c];
            u16x8 v3 = *(const u16x8*)&h[(size_t)s3 * 128 + c];
#pragma unroll
            for (int t = 0; t < 8; ++t) {
                acc[t] += b2f(v0[t]);
                acc[t] = fmaf(m1, b2f(v1[t]), acc[t]);
                acc[t] = fmaf(m2, b2f(v2[t]), acc[t]);
                acc[t] = fmaf(m3, b2f(v3[t]), acc[t]);
            }
        }
#pragma unroll
        for (int t = 0; t < 8; ++t) {
            acc[t] += __shfl_xor(acc[t], 16);
            acc[t] += __shfl_xor(acc[t], 32);
        }
        if (quarter == 0) {
            float4 b0 = *(const float4*)&bias[c];
            float4 b1 = *(const float4*)&bias[c + 4];
            float bv[8] = {b0.x, b0.y, b0.z, b0.w, b1.x, b1.y, b1.z, b1.w};
            u16x8 o;
#pragma unroll
            for (int t = 0; t < 8; ++t)
                o[t] = f2b(fmaxf(dn * (acc[t] + b2f(hv[t])) + bv[t], 0.f));
            *(u16x8*)&xt[wv * 136 + c] = o;
        }
    }
    __syncthreads();

    // ---- GEMM phase: 16x128 tile; waves 0-7 each compute one 16-col slab ----
    const int m = lane & 15;
    const int quad = lane >> 4;
    f32x4 acc2;
    acc2[0] = 0.f; acc2[1] = 0.f; acc2[2] = 0.f; acc2[3] = 0.f;
    if (wv < 8) {
        bf16x8 af[4];
#pragma unroll
        for (int kt = 0; kt < 4; ++kt)
            af[kt] = *(const bf16x8*)&xt[m * 136 + kt * 32 + quad * 8];
        const u16* Wr = &W[(wv * 16 + m) * 128 + quad * 8];
#pragma unroll
        for (int kt = 0; kt < 4; ++kt) {
            bf16x8 bf = *(const bf16x8*)&Wr[kt * 32];
            acc2 = __builtin_amdgcn_mfma_f32_16x16x32_bf16(af[kt], bf, acc2, 0, 0, 0);
        }
    }
    float4 dv = *(const float4*)&dis[node0 + quad * 4];
    __syncthreads();   // all af reads done -> xt reusable as epilogue buffer
    if (wv < 8) {
        float dm[4] = {dv.x, dv.y, dv.z, dv.w};
#pragma unroll
        for (int r = 0; r < 4; ++r)
            xt[(quad * 4 + r) * 136 + wv * 16 + m] = f2b(acc2[r] * dm[r]);
    }
    __syncthreads();
    // coalesced store: 16 rows x 128 cols = 256 u16x8, threads 0-255
    if (tid < 256) {
        int r = tid >> 4, f = tid & 15;
        *(u16x8*)&hout[(size_t)(node0 + r) * 128 + f * 8] = *(const u16x8*)&xt[r * 136 + f * 8];
    }
}

// ============================= GCN aggregation (final layer: no following gemm) =============================
__global__ __launch_bounds__(256, 8) void gather2_kernel(
        const u16* __restrict__ h_sc, const u16* __restrict__ h_fc,
        const int* __restrict__ srcs_sc, const int* __restrict__ srcs_fc,
        const int* __restrict__ off_sc, const int* __restrict__ off_fc,
        const float* __restrict__ d_sc, const float* __restrict__ d_fc,
        const float* __restrict__ b_sc, const float* __restrict__ b_fc,
        u16* __restrict__ x_sc, u16* __restrict__ x_fc) {
    int bb = blockIdx.x;
    int branch = bb >= GAT_NB;
    if (branch) bb -= GAT_NB;
    const u16* h    = branch ? h_fc : h_sc;
    const int* srcs = branch ? srcs_fc : srcs_sc;
    const int* offs = branch ? off_fc : off_sc;
    const float* dis = branch ? d_fc : d_sc;
    const float* bias = branch ? b_fc : b_sc;
    u16* xout = branch ? x_fc : x_sc;

    int node = bb * 4 + (threadIdx.x >> 6);
    int lane = threadIdx.x & 63;
    int quarter = lane >> 4;
    int c = (lane & 15) * 8;
    int beg = offs[node], end = offs[node + 1];

    u16x8 hv = *(const u16x8*)&h[(size_t)node * 128 + c];
    float dn = dis[node];

    float acc[8] = {0.f, 0.f, 0.f, 0.f, 0.f, 0.f, 0.f, 0.f};
    for (int j = beg + quarter; j < end; j += 16) {
        int o1 = (j + 4  < end) ? 4  : 0;
        int o2 = (j + 8  < end) ? 8  : 0;
        int o3 = (j + 12 < end) ? 12 : 0;
        float m1 = o1 ? 1.f : 0.f;
        float m2 = o2 ? 1.f : 0.f;
        float m3 = o3 ? 1.f : 0.f;
        int s0 = __builtin_nontemporal_load(&srcs[j]);
        int s1 = __builtin_nontemporal_load(&srcs[j + o1]);
        int s2 = __builtin_nontemporal_load(&srcs[j + o2]);
        int s3 = __builtin_nontemporal_load(&srcs[j + o3]);
        u16x8 v0 = *(const u16x8*)&h[(size_t)s0 * 128 + c];
        u16x8 v1 = *(const u16x8*)&h[(size_t)s1 * 128 + c];
        u16x8 v2 = *(const u16x8*)&h[(size_t)s2 * 128 + c];
        u16x8 v3 = *(const u16x8*)&h[(size_t)s3 * 128 + c];
#pragma unroll
        for (int t = 0; t < 8; ++t) {
            acc[t] += b2f(v0[t]);
            acc[t] = fmaf(m1, b2f(v1[t]), acc[t]);
            acc[t] = fmaf(m2, b2f(v2[t]), acc[t]);
            acc[t] = fmaf(m3, b2f(v3[t]), acc[t]);
        }
    }
#pragma unroll
    for (int t = 0; t < 8; ++t) {
        acc[t] += __shfl_xor(acc[t], 16);
        acc[t] += __shfl_xor(acc[t], 32);
    }
    if (quarter == 0) {
        float4 b0 = *(const float4*)&bias[c];
        float4 b1 = *(const float4*)&bias[c + 4];
        float bv[8] = {b0.x, b0.y, b0.z, b0.w, b1.x, b1.y, b1.z, b1.w};
        u16x8 o;
#pragma unroll
        for (int t = 0; t < 8; ++t)
            o[t] = f2b(fmaxf(dn * (acc[t] + b2f(hv[t])) + bv[t], 0.f));
        __builtin_nontemporal_store(o, (u16x8*)&xout[(size_t)node * 128 + c]);
    }
}

// ============================= pooling (batch is sorted; x is bf16, fp32 accumulate) =============================
__global__ __launch_bounds__(128) void pool2_kernel(const u16* __restrict__ x_sc,
                                                    const u16* __restrict__ x_fc,
                                                    const int* __restrict__ batch,
                                                    float* __restrict__ g_sc,
                                                    float* __restrict__ g_fc) {
    int b = blockIdx.x;
    const u16* x = (b >= PB) ? x_fc : x_sc;
    float* g     = (b >= PB) ? g_fc : g_sc;
    int blk = (b >= PB) ? b - PB : b;
    int c = threadIdx.x;
    int start = blk * 64;
    if (start >= N_NODES) return;
    int endn = min(start + 64, N_NODES);
    float acc = 0.f;
    int cur = batch[start];
    for (int i = start; i < endn; ++i) {
        int bb = batch[i];
        if (bb != cur) {
            atomicAdd(&g[(size_t)cur * 128 + c], acc);
            acc = 0.f;
            cur = bb;
        }
        acc += b2f(x[(size_t)i * 128 + c]);
    }
    atomicAdd(&g[(size_t)cur * 128 + c], acc);
}

// ============================= row L2-normalize =============================
__global__ __launch_bounds__(64) void normalize_kernel(const float* __restrict__ g_sc,
                                                       const float* __restrict__ g_fc,
                                                       float* __restrict__ n_sc,
                                                       float* __restrict__ n_fc) {
    int r = blockIdx.x & 255;
    const float* g = (blockIdx.x < 256) ? g_sc : g_fc;
    float* o = (blockIdx.x < 256) ? n_sc : n_fc;
    int c = threadIdx.x;
    float v0 = g[r * 128 + c], v1 = g[r * 128 + c + 64];
    float ss = v0 * v0 + v1 * v1;
#pragma unroll
    for (int off = 32; off; off >>= 1) ss += __shfl_xor(ss, off);
    float inv = 1.0f / fmaxf(sqrtf(ss), 1e-12f);
    o[r * 128 + c] = v0 * inv;
    o[r * 128 + c + 64] = v1 * inv;
}

// ============================= classifier head =============================
__global__ __launch_bounds__(128) void head_kernel(const float* __restrict__ g_sc,
                                                   const float* __restrict__ g_fc,
                                                   const float* __restrict__ W1,
                                                   const float* __restrict__ b1,
                                                   const float* __restrict__ W2,
                                                   const float* __restrict__ b2,
                                                   float* __restrict__ out) {
    __shared__ float cat[256];
    __shared__ float red[4];
    int i = blockIdx.x, c = threadIdx.x;
    cat[c] = g_sc[i * 128 + c];
    cat[128 + c] = g_fc[i * 128 + c];
    __syncthreads();
    float acc = b1[c];
    for (int k = 0; k < 256; ++k) acc += cat[k] * W1[k * 128 + c];
    float z = fmaxf(acc, 0.f);
    float l0 = z * W2[c * 2 + 0];
    float l1 = z * W2[c * 2 + 1];
#pragma unroll
    for (int off = 32; off; off >>= 1) {
        l0 += __shfl_xor(l0, off);
        l1 += __shfl_xor(l1, off);
    }
    if ((c & 63) == 0) {
        red[(c >> 6) * 2 + 0] = l0;
        red[(c >> 6) * 2 + 1] = l1;
    }
    __syncthreads();
    if (c == 0) {
        float L0 = red[0] + red[2] + b2[0];
        float L1 = red[1] + red[3] + b2[1];
        float m = fmaxf(L0, L1);
        float lse = m + logf(expf(L0 - m) + expf(L1 - m));
        out[i * 2 + 0] = L0 - lse;
        out[i * 2 + 1] = L1 - lse;
    }
}

// ============================= contrastive loss =============================
__global__ __launch_bounds__(256) void contrast_kernel(const float* __restrict__ n_sc,
                                                       const float* __restrict__ n_fc,
                                                       float* __restrict__ loss_acc) {
    __shared__ float arow[128];
    __shared__ float redm[4];
    __shared__ float reds[4];
    __shared__ float diag_s;
    int b = blockIdx.x;
    int i = b & 255;
    bool which = b >= 256;
    const float* A  = which ? n_fc : n_sc;
    const float* B1 = which ? n_sc : n_fc;
    const float* B2 = which ? n_fc : n_sc;
    int j = threadIdx.x;
    if (j < 128) arow[j] = A[i * 128 + j];
    __syncthreads();
    float d1 = 0.f, d2 = 0.f;
    for (int k = 0; k < 128; ++k) {
        float a = arow[k];
        d1 += a * B1[(size_t)j * 128 + k];
        d2 += a * B2[(size_t)j * 128 + k];
    }
    const float t = 2.0f;  // 1/TEMPERATURE
    float v1 = t * d1;
    float v2 = (j == i) ? 0.0f : 0.8f * t * d2;
    if (j == i) diag_s = v1;
    float m = fmaxf(v1, v2);
#pragma unroll
    for (int off = 32; off; off >>= 1) m = fmaxf(m, __shfl_xor(m, off));
    if ((j & 63) == 0) redm[j >> 6] = m;
    __syncthreads();
    m = fmaxf(fmaxf(redm[0], redm[1]), fmaxf(redm[2], redm[3]));
    float s = expf(v1 - m) + expf(v2 - m);
#pragma unroll
    for (int off = 32; off; off >>= 1) s += __shfl_xor(s, off);
    if ((j & 63) == 0) reds[j >> 6] = s;
    __syncthreads();
    if (j == 0) {
        float S = reds[0] + reds[1] + reds[2] + reds[3];
        float lse = m + logf(S);
        atomicAdd(loss_acc, lse - diag_s);
    }
}

__global__ void final_add(float* __restrict__ out, const float* __restrict__ loss) {
    int t = threadIdx.x;
    if (t < 512) out[t] += loss[0] * (1.0f / 512.0f);
}

// ============================= launch =============================

extern "C" void kernel_launch(void* const* d_in, const int* in_sizes, int n_in,
                              void* d_out, int out_size, void* d_ws, size_t ws_size,
                              hipStream_t stream) {
    const float* sc_x  = (const float*)d_in[0];
    const float* fc_x  = (const float*)d_in[1];
    const int*   sc_ei = (const int*)d_in[2];
    const int*   fc_ei = (const int*)d_in[3];
    const int*   batch = (const int*)d_in[4];
    const float* sc_W  = (const float*)d_in[5];
    const float* sc_b  = (const float*)d_in[6];
    const float* fc_W  = (const float*)d_in[7];
    const float* fc_b  = (const float*)d_in[8];
    const float* fc1_W = (const float*)d_in[9];
    const float* fc1_b = (const float*)d_in[10];
    const float* fc2_W = (const float*)d_in[11];
    const float* fc2_b = (const float*)d_in[12];
    float* out = (float*)d_out;

    const size_t NF = (size_t)N_NODES * HID;  // 12.8M elements

    float* ws = (float*)d_ws;
    float* dis_sc = ws;                // N f32 (gemm epilogue float4 reads padded by dis_fc)
    float* dis_fc = dis_sc + N_NODES;  // N f32 (padded by g arrays after)
    float* g_sc  = dis_fc + N_NODES;   // g_sc,g_fc contiguous for one memset
    float* g_fc  = g_sc + NGRAPH * HID;
    float* n_sc  = g_fc + NGRAPH * HID;
    float* n_fc  = n_sc + NGRAPH * HID;
    float* lossp = n_fc + NGRAPH * HID;  // 1 (+pad)
    u16* h_sc    = (u16*)(lossp + 4);    // NF bf16
    u16* h_fc    = h_sc + NF;
    u16* x_sc    = h_fc + NF;            // NF bf16 (ping-pong buffer with h)
    u16* x_fc    = x_sc + NF;
    u16* Wtb     = x_fc + NF;            // 6*16384 bf16 (transposed weights)
    int* srcs_sc   = (int*)(Wtb + 6 * 16384);  // E
    int* srcs_fc   = srcs_sc + N_EDGES;
    u32* tmp_sc    = (u32*)(srcs_fc + N_EDGES);  // E packed records
    u32* tmp_fc    = tmp_sc + N_EDGES;
    int* off_sc    = (int*)(tmp_fc + N_EDGES);   // N+1
    int* off_fc    = off_sc + (N_NODES + 1);
    int* bcur      = off_fc + (N_NODES + 1);     // 2*NBUCK
    int* bktcnt    = bcur + 2 * NBUCK;           // 2*NBUCK
    int* bktoff    = bktcnt + 2 * NBUCK;         // 2*(NBUCK+1)
    (void)ws_size; (void)n_in; (void)in_sizes; (void)out_size;

    // ---- CSR build (bucket-first: no per-node global atomics anywhere) ----
    hipMemsetAsync(bktcnt, 0, 2 * NBUCK * sizeof(int), stream);
    bucket_count_kernel<<<2 * ABLK, 256, 0, stream>>>(sc_ei, fc_ei, bktcnt);
    bucket_scan_kernel<<<1, 256, 0, stream>>>(bktcnt, bktoff, bcur);
    buildA_kernel<<<2 * ABLK, 256, 0, stream>>>(sc_ei, fc_ei, bcur, tmp_sc, tmp_fc);
    bucket_fin_kernel<<<2 * NBUCK, 256, 0, stream>>>(tmp_sc, tmp_fc, bktoff,
                                                     off_sc, off_fc, dis_sc, dis_fc,
                                                     srcs_sc, srcs_fc);
    convert_w_kernel<<<(6 * 16384 + 255) / 256, 256, 0, stream>>>(sc_W, fc_W, Wtb);

    // ---- layer pipeline: gemm(l0) -> fgg(l0) -> fgg(l1) -> gather(l2) ----
    // buffers ping-pong: h (h0) -> x (h1) -> h (h2) -> x (x3, pooled)
    gemm2_kernel<<<2 * GB, 256, 0, stream>>>(sc_x, fc_x, 1, Wtb, 0,
                                             dis_sc, dis_fc, h_sc, h_fc);
    fgg_kernel<<<2 * FGG_NB, 1024, 0, stream>>>(
        h_sc, h_fc, srcs_sc, srcs_fc, off_sc, off_fc, dis_sc, dis_fc,
        sc_b, fc_b, Wtb, 1, x_sc, x_fc);
    fgg_kernel<<<2 * FGG_NB, 1024, 0, stream>>>(
        x_sc, x_fc, srcs_sc, srcs_fc, off_sc, off_fc, dis_sc, dis_fc,
        sc_b + HID, fc_b + HID, Wtb, 2, h_sc, h_fc);
    gather2_kernel<<<2 * GAT_NB, 256, 0, stream>>>(
        h_sc, h_fc, srcs_sc, srcs_fc, off_sc, off_fc,
        dis_sc, dis_fc, sc_b + 2 * HID, fc_b + 2 * HID, x_sc, x_fc);

    // ---- pooling ----
    hipMemsetAsync(g_sc, 0, 2 * NGRAPH * HID * sizeof(float), stream);
    pool2_kernel<<<2 * PB, 128, 0, stream>>>(x_sc, x_fc, batch, g_sc, g_fc);

    // ---- head + contrastive ----
    normalize_kernel<<<512, 64, 0, stream>>>(g_sc, g_fc, n_sc, n_fc);
    head_kernel<<<NGRAPH, 128, 0, stream>>>(g_sc, g_fc, fc1_W, fc1_b, fc2_W, fc2_b, out);
    hipMemsetAsync(lossp, 0, sizeof(float), stream);
    contrast_kernel<<<512, 256, 0, stream>>>(n_sc, n_fc, lossp);
    final_add<<<1, 512, 0, stream>>>(out, lossp);
}

// Round 6
// 872.783 us; speedup vs baseline: 1.0215x; 1.0215x over previous
//
#include <hip/hip_runtime.h>
#include <math.h>

#define N_NODES 100000
#define N_EDGES 1600000
#define HID     128
#define NGRAPH  256
#define GB      ((N_NODES + 63) / 64)               // 1563 gemm blocks per branch
#define GAT_NB  (N_NODES / 4)                       // 25000 gather blocks per branch
#define FGG_NB  (N_NODES / 16)                      // 6250 fused gather+gemm blocks per branch
#define PB      ((N_NODES + 63) / 64)               // 1563 pool blocks per branch
#define NBUCK   ((N_NODES + 511) / 512)             // 196 buckets (512 nodes each)
#define BCAP    12288                               // arena capacity/bucket (mean 8192 + 45 sd)
#define AVPT    16
#define ABLK    ((N_EDGES + 256 * AVPT - 1) / (256 * AVPT))  // 391 edge-sweep blocks per branch

typedef unsigned short u16;
typedef unsigned int   u32;
typedef __attribute__((ext_vector_type(8))) short    bf16x8;
typedef __attribute__((ext_vector_type(4))) float    f32x4;
typedef __attribute__((ext_vector_type(8))) unsigned short u16x8;

__device__ inline float b2f(u16 u) {
    union { unsigned int i; float f; } x; x.i = ((unsigned int)u) << 16; return x.f;
}
__device__ inline u16 f2b(float f) {
    union { float f; unsigned int i; } x; x.f = f;
    unsigned int r = x.i + 0x7fff + ((x.i >> 16) & 1);   // round-to-nearest-even
    return (u16)(r >> 16);
}

// ============================= CSR build (arena single-pass, no per-node global atomics) =============================
// r5 streamline: the separate bucket-count pass is gone. buildA scatters
// packed records into fixed-capacity per-bucket arenas (BCAP >> max bucket
// load); a tiny post-scan derives CSR bucket bases from the final cursors.
// buildA also caches its AVPT edges in registers so ei is read once.

__global__ void bcur_init_kernel(int* __restrict__ bcur) {
    int t = threadIdx.x;  // one block of 512 covers 2*NBUCK=392
    if (t >= 2 * NBUCK) return;
    int k = (t >= NBUCK) ? t - NBUCK : t;
    bcur[t] = k * BCAP;
}

__global__ __launch_bounds__(256) void buildA_kernel(
        const int* __restrict__ sc_ei, const int* __restrict__ fc_ei,
        int* __restrict__ bcur,
        u32* __restrict__ tmp_sc, u32* __restrict__ tmp_fc) {
    int b = blockIdx.x;
    int branch = b >= ABLK;
    int blk = branch ? b - ABLK : b;
    const int* ei = branch ? fc_ei : sc_ei;
    u32* tmp      = branch ? tmp_fc : tmp_sc;
    int* bc       = bcur + (branch ? NBUCK : 0);

    __shared__ int hist[NBUCK];
    __shared__ int cur[NBUCK];
    int tid = threadIdx.x;
    for (int i = tid; i < NBUCK; i += 256) hist[i] = 0;
    __syncthreads();

    int e0 = blk * (256 * AVPT) + tid;
    int ss[AVPT], dd[AVPT];
#pragma unroll
    for (int k = 0; k < AVPT; ++k) {
        int e = e0 + k * 256;
        bool v = e < N_EDGES;
        ss[k] = v ? ei[e] : 0;
        dd[k] = v ? ei[N_EDGES + e] : -1;
        if (v) atomicAdd(&hist[dd[k] >> 9], 1);
    }
    __syncthreads();
    for (int i = tid; i < NBUCK; i += 256) {
        int c = hist[i];
        cur[i] = c ? atomicAdd(&bc[i], c) : 0;   // arena slot (bucket*BCAP-based)
    }
    __syncthreads();
#pragma unroll
    for (int k = 0; k < AVPT; ++k) {
        if (dd[k] >= 0) {
            int pos = atomicAdd(&cur[dd[k] >> 9], 1);
            tmp[pos] = ((u32)ss[k] << 9) | (u32)(dd[k] & 511);
        }
    }
}

// post-buildA: counts = bcur_final - bucket*BCAP; exclusive scan -> CSR bases
__global__ __launch_bounds__(256) void arena_scan_kernel(
        const int* __restrict__ bcur, int* __restrict__ bktoff) {
    __shared__ int lds[2][256];
    int tid = threadIdx.x;
    int v0 = (tid < NBUCK) ? bcur[tid] - tid * BCAP : 0;
    int v1 = (tid < NBUCK) ? bcur[NBUCK + tid] - tid * BCAP : 0;
    lds[0][tid] = v0;
    lds[1][tid] = v1;
    __syncthreads();
    for (int off = 1; off < 256; off <<= 1) {
        int t0 = (tid >= off) ? lds[0][tid - off] : 0;
        int t1 = (tid >= off) ? lds[1][tid - off] : 0;
        __syncthreads();
        lds[0][tid] += t0;
        lds[1][tid] += t1;
        __syncthreads();
    }
    if (tid < NBUCK) {
        bktoff[tid] = lds[0][tid] - v0;               // exclusive
        bktoff[(NBUCK + 1) + tid] = lds[1][tid] - v1;
    }
    if (tid == 0) {
        bktoff[NBUCK] = N_EDGES;
        bktoff[(NBUCK + 1) + NBUCK] = N_EDGES;
    }
}

// per-bucket finalize: LDS degree count -> off[]+dis[], LDS-cursor scatter -> srcs
__global__ __launch_bounds__(256) void bucket_fin_kernel(
        const u32* __restrict__ tmp_sc, const u32* __restrict__ tmp_fc,
        const int* __restrict__ bcur, const int* __restrict__ bktoff,
        int* __restrict__ off_sc, int* __restrict__ off_fc,
        float* __restrict__ d_sc, float* __restrict__ d_fc,
        int* __restrict__ srcs_sc, int* __restrict__ srcs_fc) {
    int b = blockIdx.x;
    int branch = b >= NBUCK;
    int bucket = branch ? b - NBUCK : b;
    const u32* tmp = branch ? tmp_fc : tmp_sc;
    const int* bo  = bktoff + (branch ? (NBUCK + 1) : 0);
    int* off   = branch ? off_fc : off_sc;
    float* dis = branch ? d_fc : d_sc;
    int* srcs  = branch ? srcs_fc : srcs_sc;
    int node0 = bucket << 9;
    int beg_t = bucket * BCAP;                       // arena range
    int end_t = bcur[branch * NBUCK + bucket];
    int csr0  = bo[bucket];                          // CSR base of this bucket

    __shared__ int cnt[512];
    __shared__ int cur[512];
    __shared__ int psum[256];
    int tid = threadIdx.x;
    cnt[2 * tid] = 0; cnt[2 * tid + 1] = 0;
    __syncthreads();
    for (int r = beg_t + tid; r < end_t; r += 256)
        atomicAdd(&cnt[tmp[r] & 511], 1);
    __syncthreads();
    int c0 = cnt[2 * tid], c1 = cnt[2 * tid + 1];
    int s = c0 + c1;
    psum[tid] = s;
    __syncthreads();
    for (int o = 1; o < 256; o <<= 1) {
        int t = (tid >= o) ? psum[tid - o] : 0;
        __syncthreads();
        psum[tid] += t;
        __syncthreads();
    }
    int base = csr0 + psum[tid] - s;   // exclusive start of node 2*tid
    int n0 = node0 + 2 * tid, n1 = node0 + 2 * tid + 1;
    if (n0 < N_NODES) { off[n0] = base;      dis[n0] = rsqrtf((float)c0 + 1.0f); }
    if (n1 < N_NODES) { off[n1] = base + c0; dis[n1] = rsqrtf((float)c1 + 1.0f); }
    cur[2 * tid] = base;
    cur[2 * tid + 1] = base + c0;
    __syncthreads();
    for (int r = beg_t + tid; r < end_t; r += 256) {
        u32 rec = tmp[r];
        int pos = atomicAdd(&cur[rec & 511], 1);
        srcs[pos] = rec >> 9;
    }
    if (b == 0 && tid == 0) { off_sc[N_NODES] = N_EDGES; off_fc[N_NODES] = N_EDGES; }
}

// ---- pre-convert+transpose weights: Wt[l'][n][k] = W[l][k][n] (bf16), l' = branch*3+l ----
__global__ void convert_w_kernel(const float* __restrict__ sc_W, const float* __restrict__ fc_W,
                                 u16* __restrict__ Wt) {
    int idx = blockIdx.x * 256 + threadIdx.x;  // 6*16384 total
    if (idx >= 6 * 16384) return;
    int lp = idx >> 14;
    int r = idx & 16383;
    int n = r >> 7, k = r & 127;
    const float* W = (lp >= 3) ? fc_W : sc_W;
    int l = (lp >= 3) ? lp - 3 : lp;
    Wt[idx] = f2b(W[(size_t)l * 16384 + k * 128 + n]);
}

// ============================= MFMA GEMM (layer 0 only: fp32 input, LDS-staged) =============================
__global__ __launch_bounds__(256) void gemm2_kernel(
        const void* __restrict__ A_sc, const void* __restrict__ A_fc, int a_fp32,
        const u16* __restrict__ Wt, int layer,
        const float* __restrict__ d_sc, const float* __restrict__ d_fc,
        u16* __restrict__ H_sc, u16* __restrict__ H_fc) {
    int branch = blockIdx.x >= GB;
    int blk = branch ? blockIdx.x - GB : blockIdx.x;
    const void* A = branch ? A_fc : A_sc;
    const float* dis = branch ? d_fc : d_sc;
    u16* H = branch ? H_fc : H_sc;
    const u16* W = Wt + (((size_t)branch * 3 + layer) << 14);

    __shared__ u16 Alds[64 * 136];   // rows padded to 136 u16 (272 B)
    __shared__ u16 Wlds[128 * 136];  // Wt rows: n-major, k contiguous
    const int tid = threadIdx.x;
    const int row0 = blk * 64;

    if (a_fp32) {
        const float* Af = (const float*)A;
#pragma unroll
        for (int i = 0; i < 8; ++i) {
            int idx = tid + i * 256;
            int r = idx >> 5, f = idx & 31;
            int grow = row0 + r;
            float4 v = (grow < N_NODES) ? *(const float4*)&Af[(size_t)grow * 128 + f * 4]
                                        : make_float4(0.f, 0.f, 0.f, 0.f);
            ushort4 o;
            o.x = f2b(v.x); o.y = f2b(v.y); o.z = f2b(v.z); o.w = f2b(v.w);
            *(ushort4*)&Alds[r * 136 + f * 4] = o;
        }
    } else {
        const u16* Ab = (const u16*)A;
#pragma unroll
        for (int i = 0; i < 4; ++i) {
            int idx = tid + i * 256;
            int r = idx >> 4, f = idx & 15;
            int grow = row0 + r;
            u16x8 v = {};
            if (grow < N_NODES) v = *(const u16x8*)&Ab[(size_t)grow * 128 + f * 8];
            *(u16x8*)&Alds[r * 136 + f * 8] = v;
        }
    }
#pragma unroll
    for (int i = 0; i < 8; ++i) {
        int idx = tid + i * 256;
        int n = idx >> 4, f = idx & 15;
        *(u16x8*)&Wlds[n * 136 + f * 8] = *(const u16x8*)&W[n * 128 + f * 8];
    }
    __syncthreads();

    const int wv = tid >> 6;
    const int lane = tid & 63;
    const int m = lane & 15;       // row (A) / col (B) within 16-tile
    const int quad = lane >> 4;    // k-subchunk

    bf16x8 af[4];
#pragma unroll
    for (int kt = 0; kt < 4; ++kt)
        af[kt] = *(const bf16x8*)&Alds[(wv * 16 + m) * 136 + kt * 32 + quad * 8];

    f32x4 acc[8];
#pragma unroll
    for (int ct = 0; ct < 8; ++ct) { acc[ct][0] = 0.f; acc[ct][1] = 0.f; acc[ct][2] = 0.f; acc[ct][3] = 0.f; }

#pragma unroll
    for (int ct = 0; ct < 8; ++ct) {
#pragma unroll
        for (int kt = 0; kt < 4; ++kt) {
            bf16x8 bf = *(const bf16x8*)&Wlds[(ct * 16 + m) * 136 + kt * 32 + quad * 8];
            acc[ct] = __builtin_amdgcn_mfma_f32_16x16x32_bf16(af[kt], bf, acc[ct], 0, 0, 0);
        }
    }

    float4 dv = *(const float4*)&dis[row0 + wv * 16 + quad * 4];  // ws-padded, OOB-safe
#pragma unroll
    for (int ct = 0; ct < 8; ++ct) {
        acc[ct][0] *= dv.x; acc[ct][1] *= dv.y; acc[ct][2] *= dv.z; acc[ct][3] *= dv.w;
    }

#pragma unroll
    for (int ct = 0; ct < 8; ++ct)
#pragma unroll
        for (int r = 0; r < 4; ++r)
            Alds[(wv * 16 + quad * 4 + r) * 136 + ct * 16 + m] = f2b(acc[ct][r]);
    __syncthreads();
#pragma unroll
    for (int i = 0; i < 4; ++i) {
        int idx = i * 64 + lane;
        int r = idx >> 4, f = idx & 15;
        int grow = row0 + wv * 16 + r;
        if (grow < N_NODES)
            *(u16x8*)&H[(size_t)grow * 128 + f * 8] = *(const u16x8*)&Alds[(wv * 16 + r) * 136 + f * 8];
    }
}

// ============================= fused gather(l) + gemm(l+1)  (r4-v1 structure, single-branch) =============================
// r4/r5 lesson: barrier-coupled fusion costs ~15-20% on the gather phase and
// the coupling scope is the lever: 4-wave blocks (v1, 186us) beat 16-wave
// (v2, 192us). Revert to v1; launch per-branch to halve the instantaneous
// random working set (25.6MB vs 51.2MB) for L2 locality.
__global__ __launch_bounds__(256, 6) void fgg_kernel(
        const u16* __restrict__ h, const int* __restrict__ srcs,
        const int* __restrict__ offs, const float* __restrict__ dis,
        const float* __restrict__ bias,          // bias of layer l
        const u16* __restrict__ W,               // weight layer l+1 (pre-offset)
        u16* __restrict__ hout) {
    int bb = blockIdx.x;
    __shared__ u16 xt[16 * 136];   // x tile; reused as epilogue transpose buffer

    const int tid = threadIdx.x;
    const int wv = tid >> 6;
    const int lane = tid & 63;
    const int quarter = lane >> 4;
    const int c = (lane & 15) * 8;
    const int node0 = bb * 16;     // N_NODES = 6250*16 exactly -> no OOB

    // ---- gather phase: 4 sequential nodes per wave ----
    for (int nn = 0; nn < 4; ++nn) {
        int node = node0 + wv * 4 + nn;
        int beg = offs[node], end = offs[node + 1];
        u16x8 hv = *(const u16x8*)&h[(size_t)node * 128 + c];
        float dn = dis[node];
        float acc[8] = {0.f, 0.f, 0.f, 0.f, 0.f, 0.f, 0.f, 0.f};
        for (int j = beg + quarter; j < end; j += 16) {
            int o1 = (j + 4  < end) ? 4  : 0;
            int o2 = (j + 8  < end) ? 8  : 0;
            int o3 = (j + 12 < end) ? 12 : 0;
            float m1 = o1 ? 1.f : 0.f;
            float m2 = o2 ? 1.f : 0.f;
            float m3 = o3 ? 1.f : 0.f;
            int s0 = __builtin_nontemporal_load(&srcs[j]);
            int s1 = __builtin_nontemporal_load(&srcs[j + o1]);
            int s2 = __builtin_nontemporal_load(&srcs[j + o2]);
            int s3 = __builtin_nontemporal_load(&srcs[j + o3]);
            u16x8 v0 = *(const u16x8*)&h[(size_t)s0 * 128 + c];
            u16x8 v1 = *(const u16x8*)&h[(size_t)s1 * 128 + c];
            u16x8 v2 = *(const u16x8*)&h[(size_t)s2 * 128 + c];
            u16x8 v3 = *(const u16x8*)&h[(size_t)s3 * 128 + c];
#pragma unroll
            for (int t = 0; t < 8; ++t) {
                acc[t] += b2f(v0[t]);
                acc[t] = fmaf(m1, b2f(v1[t]), acc[t]);
                acc[t] = fmaf(m2, b2f(v2[t]), acc[t]);
                acc[t] = fmaf(m3, b2f(v3[t]), acc[t]);
            }
        }
#pragma unroll
        for (int t = 0; t < 8; ++t) {
            acc[t] += __shfl_xor(acc[t], 16);
            acc[t] += __shfl_xor(acc[t], 32);
        }
        if (quarter == 0) {
            float4 b0 = *(const float4*)&bias[c];
            float4 b1 = *(const float4*)&bias[c + 4];
            float bv[8] = {b0.x, b0.y, b0.z, b0.w, b1.x, b1.y, b1.z, b1.w};
            u16x8 o;
#pragma unroll
            for (int t = 0; t < 8; ++t)
                o[t] = f2b(fmaxf(dn * (acc[t] + b2f(hv[t])) + bv[t], 0.f));
            *(u16x8*)&xt[(wv * 4 + nn) * 136 + c] = o;
        }
    }
    __syncthreads();

    // ---- GEMM phase: 16x128 tile, wave wv computes cols [wv*32, wv*32+32) ----
    const int m = lane & 15;
    const int quad = lane >> 4;
    bf16x8 af[4];
#pragma unroll
    for (int kt = 0; kt < 4; ++kt)
        af[kt] = *(const bf16x8*)&xt[m * 136 + kt * 32 + quad * 8];

    f32x4 acc2[2];
    acc2[0][0] = 0.f; acc2[0][1] = 0.f; acc2[0][2] = 0.f; acc2[0][3] = 0.f;
    acc2[1][0] = 0.f; acc2[1][1] = 0.f; acc2[1][2] = 0.f; acc2[1][3] = 0.f;
#pragma unroll
    for (int cc = 0; cc < 2; ++cc) {
        int ct = wv * 2 + cc;
        const u16* Wr = &W[(ct * 16 + m) * 128 + quad * 8];
#pragma unroll
        for (int kt = 0; kt < 4; ++kt) {
            bf16x8 bf = *(const bf16x8*)&Wr[kt * 32];
            acc2[cc] = __builtin_amdgcn_mfma_f32_16x16x32_bf16(af[kt], bf, acc2[cc], 0, 0, 0);
        }
    }
    float4 dv = *(const float4*)&dis[node0 + quad * 4];
    __syncthreads();   // all af reads done -> xt reusable as epilogue buffer
#pragma unroll
    for (int cc = 0; cc < 2; ++cc) {
        float dm[4] = {dv.x, dv.y, dv.z, dv.w};
#pragma unroll
        for (int r = 0; r < 4; ++r)
            xt[(quad * 4 + r) * 136 + (wv * 2 + cc) * 16 + m] = f2b(acc2[cc][r] * dm[r]);
    }
    __syncthreads();
    // coalesced store: 16 rows x 128 cols = 256 u16x8, one per thread
    {
        int r = tid >> 4, f = tid & 15;
        *(u16x8*)&hout[(size_t)(node0 + r) * 128 + f * 8] = *(const u16x8*)&xt[r * 136 + f * 8];
    }
}

// ============================= GCN aggregation (final layer; single-branch dispatch) =============================
__global__ __launch_bounds__(256, 8) void gather2_kernel(
        const u16* __restrict__ h, const int* __restrict__ srcs,
        const int* __restrict__ offs, const float* __restrict__ dis,
        const float* __restrict__ bias, u16* __restrict__ xout) {
    int bb = blockIdx.x;
    int node = bb * 4 + (threadIdx.x >> 6);
    int lane = threadIdx.x & 63;
    int quarter = lane >> 4;
    int c = (lane & 15) * 8;
    int beg = offs[node], end = offs[node + 1];

    u16x8 hv = *(const u16x8*)&h[(size_t)node * 128 + c];
    float dn = dis[node];

    float acc[8] = {0.f, 0.f, 0.f, 0.f, 0.f, 0.f, 0.f, 0.f};
    for (int j = beg + quarter; j < end; j += 16) {
        int o1 = (j + 4  < end) ? 4  : 0;
        int o2 = (j + 8  < end) ? 8  : 0;
        int o3 = (j + 12 < end) ? 12 : 0;
        float m1 = o1 ? 1.f : 0.f;
        float m2 = o2 ? 1.f : 0.f;
        float m3 = o3 ? 1.f : 0.f;
        int s0 = __builtin_nontemporal_load(&srcs[j]);
        int s1 = __builtin_nontemporal_load(&srcs[j + o1]);
        int s2 = __builtin_nontemporal_load(&srcs[j + o2]);
        int s3 = __builtin_nontemporal_load(&srcs[j + o3]);
        u16x8 v0 = *(const u16x8*)&h[(size_t)s0 * 128 + c];
        u16x8 v1 = *(const u16x8*)&h[(size_t)s1 * 128 + c];
        u16x8 v2 = *(const u16x8*)&h[(size_t)s2 * 128 + c];
        u16x8 v3 = *(const u16x8*)&h[(size_t)s3 * 128 + c];
#pragma unroll
        for (int t = 0; t < 8; ++t) {
            acc[t] += b2f(v0[t]);
            acc[t] = fmaf(m1, b2f(v1[t]), acc[t]);
            acc[t] = fmaf(m2, b2f(v2[t]), acc[t]);
            acc[t] = fmaf(m3, b2f(v3[t]), acc[t]);
        }
    }
#pragma unroll
    for (int t = 0; t < 8; ++t) {
        acc[t] += __shfl_xor(acc[t], 16);
        acc[t] += __shfl_xor(acc[t], 32);
    }
    if (quarter == 0) {
        float4 b0 = *(const float4*)&bias[c];
        float4 b1 = *(const float4*)&bias[c + 4];
        float bv[8] = {b0.x, b0.y, b0.z, b0.w, b1.x, b1.y, b1.z, b1.w};
        u16x8 o;
#pragma unroll
        for (int t = 0; t < 8; ++t)
            o[t] = f2b(fmaxf(dn * (acc[t] + b2f(hv[t])) + bv[t], 0.f));
        __builtin_nontemporal_store(o, (u16x8*)&xout[(size_t)node * 128 + c]);
    }
}

// ============================= pooling (batch is sorted; x is bf16, fp32 accumulate) =============================
__global__ __launch_bounds__(128) void pool2_kernel(const u16* __restrict__ x_sc,
                                                    const u16* __restrict__ x_fc,
                                                    const int* __restrict__ batch,
                                                    float* __restrict__ g_sc,
                                                    float* __restrict__ g_fc) {
    int b = blockIdx.x;
    const u16* x = (b >= PB) ? x_fc : x_sc;
    float* g     = (b >= PB) ? g_fc : g_sc;
    int blk = (b >= PB) ? b - PB : b;
    int c = threadIdx.x;
    int start = blk * 64;
    if (start >= N_NODES) return;
    int endn = min(start + 64, N_NODES);
    float acc = 0.f;
    int cur = batch[start];
    for (int i = start; i < endn; ++i) {
        int bb = batch[i];
        if (bb != cur) {
            atomicAdd(&g[(size_t)cur * 128 + c], acc);
            acc = 0.f;
            cur = bb;
        }
        acc += b2f(x[(size_t)i * 128 + c]);
    }
    atomicAdd(&g[(size_t)cur * 128 + c], acc);
}

// ============================= row L2-normalize =============================
__global__ __launch_bounds__(64) void normalize_kernel(const float* __restrict__ g_sc,
                                                       const float* __restrict__ g_fc,
                                                       float* __restrict__ n_sc,
                                                       float* __restrict__ n_fc) {
    int r = blockIdx.x & 255;
    const float* g = (blockIdx.x < 256) ? g_sc : g_fc;
    float* o = (blockIdx.x < 256) ? n_sc : n_fc;
    int c = threadIdx.x;
    float v0 = g[r * 128 + c], v1 = g[r * 128 + c + 64];
    float ss = v0 * v0 + v1 * v1;
#pragma unroll
    for (int off = 32; off; off >>= 1) ss += __shfl_xor(ss, off);
    float inv = 1.0f / fmaxf(sqrtf(ss), 1e-12f);
    o[r * 128 + c] = v0 * inv;
    o[r * 128 + c + 64] = v1 * inv;
}

// ============================= classifier head =============================
__global__ __launch_bounds__(128) void head_kernel(const float* __restrict__ g_sc,
                                                   const float* __restrict__ g_fc,
                                                   const float* __restrict__ W1,
                                                   const float* __restrict__ b1,
                                                   const float* __restrict__ W2,
                                                   const float* __restrict__ b2,
                                                   float* __restrict__ out) {
    __shared__ float cat[256];
    __shared__ float red[4];
    int i = blockIdx.x, c = threadIdx.x;
    cat[c] = g_sc[i * 128 + c];
    cat[128 + c] = g_fc[i * 128 + c];
    __syncthreads();
    float acc = b1[c];
    for (int k = 0; k < 256; ++k) acc += cat[k] * W1[k * 128 + c];
    float z = fmaxf(acc, 0.f);
    float l0 = z * W2[c * 2 + 0];
    float l1 = z * W2[c * 2 + 1];
#pragma unroll
    for (int off = 32; off; off >>= 1) {
        l0 += __shfl_xor(l0, off);
        l1 += __shfl_xor(l1, off);
    }
    if ((c & 63) == 0) {
        red[(c >> 6) * 2 + 0] = l0;
        red[(c >> 6) * 2 + 1] = l1;
    }
    __syncthreads();
    if (c == 0) {
        float L0 = red[0] + red[2] + b2[0];
        float L1 = red[1] + red[3] + b2[1];
        float m = fmaxf(L0, L1);
        float lse = m + logf(expf(L0 - m) + expf(L1 - m));
        out[i * 2 + 0] = L0 - lse;
        out[i * 2 + 1] = L1 - lse;
    }
}

// ============================= contrastive loss =============================
__global__ __launch_bounds__(256) void contrast_kernel(const float* __restrict__ n_sc,
                                                       const float* __restrict__ n_fc,
                                                       float* __restrict__ loss_acc) {
    __shared__ float arow[128];
    __shared__ float redm[4];
    __shared__ float reds[4];
    __shared__ float diag_s;
    int b = blockIdx.x;
    int i = b & 255;
    bool which = b >= 256;
    const float* A  = which ? n_fc : n_sc;
    const float* B1 = which ? n_sc : n_fc;
    const float* B2 = which ? n_fc : n_sc;
    int j = threadIdx.x;
    if (j < 128) arow[j] = A[i * 128 + j];
    __syncthreads();
    float d1 = 0.f, d2 = 0.f;
    for (int k = 0; k < 128; ++k) {
        float a = arow[k];
        d1 += a * B1[(size_t)j * 128 + k];
        d2 += a * B2[(size_t)j * 128 + k];
    }
    const float t = 2.0f;  // 1/TEMPERATURE
    float v1 = t * d1;
    float v2 = (j == i) ? 0.0f : 0.8f * t * d2;
    if (j == i) diag_s = v1;
    float m = fmaxf(v1, v2);
#pragma unroll
    for (int off = 32; off; off >>= 1) m = fmaxf(m, __shfl_xor(m, off));
    if ((j & 63) == 0) redm[j >> 6] = m;
    __syncthreads();
    m = fmaxf(fmaxf(redm[0], redm[1]), fmaxf(redm[2], redm[3]));
    float s = expf(v1 - m) + expf(v2 - m);
#pragma unroll
    for (int off = 32; off; off >>= 1) s += __shfl_xor(s, off);
    if ((j & 63) == 0) reds[j >> 6] = s;
    __syncthreads();
    if (j == 0) {
        float S = reds[0] + reds[1] + reds[2] + reds[3];
        float lse = m + logf(S);
        atomicAdd(loss_acc, lse - diag_s);
    }
}

__global__ void final_add(float* __restrict__ out, const float* __restrict__ loss) {
    int t = threadIdx.x;
    if (t < 512) out[t] += loss[0] * (1.0f / 512.0f);
}

// ============================= launch =============================

extern "C" void kernel_launch(void* const* d_in, const int* in_sizes, int n_in,
                              void* d_out, int out_size, void* d_ws, size_t ws_size,
                              hipStream_t stream) {
    const float* sc_x  = (const float*)d_in[0];
    const float* fc_x  = (const float*)d_in[1];
    const int*   sc_ei = (const int*)d_in[2];
    const int*   fc_ei = (const int*)d_in[3];
    const int*   batch = (const int*)d_in[4];
    const float* sc_W  = (const float*)d_in[5];
    const float* sc_b  = (const float*)d_in[6];
    const float* fc_W  = (const float*)d_in[7];
    const float* fc_b  = (const float*)d_in[8];
    const float* fc1_W = (const float*)d_in[9];
    const float* fc1_b = (const float*)d_in[10];
    const float* fc2_W = (const float*)d_in[11];
    const float* fc2_b = (const float*)d_in[12];
    float* out = (float*)d_out;

    const size_t NF = (size_t)N_NODES * HID;     // 12.8M elements
    const size_t TMPSZ = (size_t)NBUCK * BCAP;   // arena records per branch

    float* ws = (float*)d_ws;
    float* dis_sc = ws;                // N f32 (gemm epilogue float4 reads padded by dis_fc)
    float* dis_fc = dis_sc + N_NODES;  // N f32 (padded by g arrays after)
    float* g_sc  = dis_fc + N_NODES;   // g_sc,g_fc contiguous for one memset
    float* g_fc  = g_sc + NGRAPH * HID;
    float* n_sc  = g_fc + NGRAPH * HID;
    float* n_fc  = n_sc + NGRAPH * HID;
    float* lossp = n_fc + NGRAPH * HID;  // 1 (+pad)
    u16* h_sc    = (u16*)(lossp + 4);    // NF bf16
    u16* h_fc    = h_sc + NF;
    u16* x_sc    = h_fc + NF;            // NF bf16 (ping-pong buffer with h)
    u16* x_fc    = x_sc + NF;
    u16* Wtb     = x_fc + NF;            // 6*16384 bf16 (transposed weights)
    int* srcs_sc   = (int*)(Wtb + 6 * 16384);  // E
    int* srcs_fc   = srcs_sc + N_EDGES;
    u32* tmp_sc    = (u32*)(srcs_fc + N_EDGES);  // NBUCK*BCAP arena records
    u32* tmp_fc    = tmp_sc + TMPSZ;
    int* off_sc    = (int*)(tmp_fc + TMPSZ);     // N+1
    int* off_fc    = off_sc + (N_NODES + 1);
    int* bcur      = off_fc + (N_NODES + 1);     // 2*NBUCK
    int* bktoff    = bcur + 2 * NBUCK;           // 2*(NBUCK+1)
    (void)ws_size; (void)n_in; (void)in_sizes; (void)out_size;

    // ---- CSR build (single edge pass into arenas) ----
    bcur_init_kernel<<<1, 512, 0, stream>>>(bcur);
    buildA_kernel<<<2 * ABLK, 256, 0, stream>>>(sc_ei, fc_ei, bcur, tmp_sc, tmp_fc);
    arena_scan_kernel<<<1, 256, 0, stream>>>(bcur, bktoff);
    bucket_fin_kernel<<<2 * NBUCK, 256, 0, stream>>>(tmp_sc, tmp_fc, bcur, bktoff,
                                                     off_sc, off_fc, dis_sc, dis_fc,
                                                     srcs_sc, srcs_fc);
    convert_w_kernel<<<(6 * 16384 + 255) / 256, 256, 0, stream>>>(sc_W, fc_W, Wtb);

    // ---- layer pipeline: gemm(l0) -> fgg(l0) -> fgg(l1) -> gather(l2), per-branch dispatches ----
    // buffers ping-pong: h (h0) -> x (h1) -> h (h2) -> x (x3, pooled)
    gemm2_kernel<<<2 * GB, 256, 0, stream>>>(sc_x, fc_x, 1, Wtb, 0,
                                             dis_sc, dis_fc, h_sc, h_fc);
    fgg_kernel<<<FGG_NB, 256, 0, stream>>>(h_sc, srcs_sc, off_sc, dis_sc,
                                           sc_b, Wtb + ((size_t)1 << 14), x_sc);
    fgg_kernel<<<FGG_NB, 256, 0, stream>>>(h_fc, srcs_fc, off_fc, dis_fc,
                                           fc_b, Wtb + ((size_t)4 << 14), x_fc);
    fgg_kernel<<<FGG_NB, 256, 0, stream>>>(x_sc, srcs_sc, off_sc, dis_sc,
                                           sc_b + HID, Wtb + ((size_t)2 << 14), h_sc);
    fgg_kernel<<<FGG_NB, 256, 0, stream>>>(x_fc, srcs_fc, off_fc, dis_fc,
                                           fc_b + HID, Wtb + ((size_t)5 << 14), h_fc);
    gather2_kernel<<<GAT_NB, 256, 0, stream>>>(h_sc, srcs_sc, off_sc, dis_sc,
                                               sc_b + 2 * HID, x_sc);
    gather2_kernel<<<GAT_NB, 256, 0, stream>>>(h_fc, srcs_fc, off_fc, dis_fc,
                                               fc_b + 2 * HID, x_fc);

    // ---- pooling ----
    hipMemsetAsync(g_sc, 0, 2 * NGRAPH * HID * sizeof(float), stream);
    pool2_kernel<<<2 * PB, 128, 0, stream>>>(x_sc, x_fc, batch, g_sc, g_fc);

    // ---- head + contrastive ----
    normalize_kernel<<<512, 64, 0, stream>>>(g_sc, g_fc, n_sc, n_fc);
    head_kernel<<<NGRAPH, 128, 0, stream>>>(g_sc, g_fc, fc1_W, fc1_b, fc2_W, fc2_b, out);
    hipMemsetAsync(lossp, 0, sizeof(float), stream);
    contrast_kernel<<<512, 256, 0, stream>>>(n_sc, n_fc, lossp);
    final_add<<<1, 512, 0, stream>>>(out, lossp);
}

// Round 7
// 839.240 us; speedup vs baseline: 1.0623x; 1.0400x over previous
//
#include <hip/hip_runtime.h>
#include <math.h>

#define N_NODES 100000
#define N_EDGES 1600000
#define HID     128
#define NGRAPH  256
#define GB      ((N_NODES + 63) / 64)               // 1563 gemm blocks per branch
#define GAT_NB  (N_NODES / 4)                       // 25000 gather blocks per branch
#define FGG_NB  (N_NODES / 16)                      // 6250 fused gather+gemm blocks per branch
#define PB      ((N_NODES + 63) / 64)               // 1563 pool blocks per branch
#define NBUCK   ((N_NODES + 511) / 512)             // 196 buckets (512 nodes each)
#define BCAP    12288                               // arena capacity/bucket (mean 8192 + 45 sd)
#define AVPT    16
#define ABLK    ((N_EDGES + 256 * AVPT - 1) / (256 * AVPT))  // 391 edge-sweep blocks per branch

typedef unsigned short u16;
typedef unsigned int   u32;
typedef __attribute__((ext_vector_type(8))) short    bf16x8;
typedef __attribute__((ext_vector_type(4))) float    f32x4;
typedef __attribute__((ext_vector_type(8))) unsigned short u16x8;

__device__ inline float b2f(u16 u) {
    union { unsigned int i; float f; } x; x.i = ((unsigned int)u) << 16; return x.f;
}
__device__ inline u16 f2b(float f) {
    union { float f; unsigned int i; } x; x.f = f;
    unsigned int r = x.i + 0x7fff + ((x.i >> 16) & 1);   // round-to-nearest-even
    return (u16)(r >> 16);
}

// ============================= CSR build (arena single-pass, no per-node global atomics) =============================

__global__ void bcur_init_kernel(int* __restrict__ bcur) {
    int t = threadIdx.x;  // one block of 512 covers 2*NBUCK=392
    if (t >= 2 * NBUCK) return;
    int k = (t >= NBUCK) ? t - NBUCK : t;
    bcur[t] = k * BCAP;
}

__global__ __launch_bounds__(256) void buildA_kernel(
        const int* __restrict__ sc_ei, const int* __restrict__ fc_ei,
        int* __restrict__ bcur,
        u32* __restrict__ tmp_sc, u32* __restrict__ tmp_fc) {
    int b = blockIdx.x;
    int branch = b >= ABLK;
    int blk = branch ? b - ABLK : b;
    const int* ei = branch ? fc_ei : sc_ei;
    u32* tmp      = branch ? tmp_fc : tmp_sc;
    int* bc       = bcur + (branch ? NBUCK : 0);

    __shared__ int hist[NBUCK];
    __shared__ int cur[NBUCK];
    int tid = threadIdx.x;
    for (int i = tid; i < NBUCK; i += 256) hist[i] = 0;
    __syncthreads();

    int e0 = blk * (256 * AVPT) + tid;
    int ss[AVPT], dd[AVPT];
#pragma unroll
    for (int k = 0; k < AVPT; ++k) {
        int e = e0 + k * 256;
        bool v = e < N_EDGES;
        ss[k] = v ? ei[e] : 0;
        dd[k] = v ? ei[N_EDGES + e] : -1;
        if (v) atomicAdd(&hist[dd[k] >> 9], 1);
    }
    __syncthreads();
    for (int i = tid; i < NBUCK; i += 256) {
        int c = hist[i];
        cur[i] = c ? atomicAdd(&bc[i], c) : 0;   // arena slot (bucket*BCAP-based)
    }
    __syncthreads();
#pragma unroll
    for (int k = 0; k < AVPT; ++k) {
        if (dd[k] >= 0) {
            int pos = atomicAdd(&cur[dd[k] >> 9], 1);
            tmp[pos] = ((u32)ss[k] << 9) | (u32)(dd[k] & 511);
        }
    }
}

// post-buildA: counts = bcur_final - bucket*BCAP; exclusive scan -> CSR bases
__global__ __launch_bounds__(256) void arena_scan_kernel(
        const int* __restrict__ bcur, int* __restrict__ bktoff) {
    __shared__ int lds[2][256];
    int tid = threadIdx.x;
    int v0 = (tid < NBUCK) ? bcur[tid] - tid * BCAP : 0;
    int v1 = (tid < NBUCK) ? bcur[NBUCK + tid] - tid * BCAP : 0;
    lds[0][tid] = v0;
    lds[1][tid] = v1;
    __syncthreads();
    for (int off = 1; off < 256; off <<= 1) {
        int t0 = (tid >= off) ? lds[0][tid - off] : 0;
        int t1 = (tid >= off) ? lds[1][tid - off] : 0;
        __syncthreads();
        lds[0][tid] += t0;
        lds[1][tid] += t1;
        __syncthreads();
    }
    if (tid < NBUCK) {
        bktoff[tid] = lds[0][tid] - v0;               // exclusive
        bktoff[(NBUCK + 1) + tid] = lds[1][tid] - v1;
    }
    if (tid == 0) {
        bktoff[NBUCK] = N_EDGES;
        bktoff[(NBUCK + 1) + NBUCK] = N_EDGES;
    }
}

// per-bucket finalize: LDS degree count -> off[]+dis[], LDS-cursor scatter -> srcs
__global__ __launch_bounds__(256) void bucket_fin_kernel(
        const u32* __restrict__ tmp_sc, const u32* __restrict__ tmp_fc,
        const int* __restrict__ bcur, const int* __restrict__ bktoff,
        int* __restrict__ off_sc, int* __restrict__ off_fc,
        float* __restrict__ d_sc, float* __restrict__ d_fc,
        int* __restrict__ srcs_sc, int* __restrict__ srcs_fc) {
    int b = blockIdx.x;
    int branch = b >= NBUCK;
    int bucket = branch ? b - NBUCK : b;
    const u32* tmp = branch ? tmp_fc : tmp_sc;
    const int* bo  = bktoff + (branch ? (NBUCK + 1) : 0);
    int* off   = branch ? off_fc : off_sc;
    float* dis = branch ? d_fc : d_sc;
    int* srcs  = branch ? srcs_fc : srcs_sc;
    int node0 = bucket << 9;
    int beg_t = bucket * BCAP;                       // arena range
    int end_t = bcur[branch * NBUCK + bucket];
    int csr0  = bo[bucket];                          // CSR base of this bucket

    __shared__ int cnt[512];
    __shared__ int cur[512];
    __shared__ int psum[256];
    int tid = threadIdx.x;
    cnt[2 * tid] = 0; cnt[2 * tid + 1] = 0;
    __syncthreads();
    for (int r = beg_t + tid; r < end_t; r += 256)
        atomicAdd(&cnt[tmp[r] & 511], 1);
    __syncthreads();
    int c0 = cnt[2 * tid], c1 = cnt[2 * tid + 1];
    int s = c0 + c1;
    psum[tid] = s;
    __syncthreads();
    for (int o = 1; o < 256; o <<= 1) {
        int t = (tid >= o) ? psum[tid - o] : 0;
        __syncthreads();
        psum[tid] += t;
        __syncthreads();
    }
    int base = csr0 + psum[tid] - s;   // exclusive start of node 2*tid
    int n0 = node0 + 2 * tid, n1 = node0 + 2 * tid + 1;
    if (n0 < N_NODES) { off[n0] = base;      dis[n0] = rsqrtf((float)c0 + 1.0f); }
    if (n1 < N_NODES) { off[n1] = base + c0; dis[n1] = rsqrtf((float)c1 + 1.0f); }
    cur[2 * tid] = base;
    cur[2 * tid + 1] = base + c0;
    __syncthreads();
    for (int r = beg_t + tid; r < end_t; r += 256) {
        u32 rec = tmp[r];
        int pos = atomicAdd(&cur[rec & 511], 1);
        srcs[pos] = rec >> 9;
    }
    if (b == 0 && tid == 0) { off_sc[N_NODES] = N_EDGES; off_fc[N_NODES] = N_EDGES; }
}

// ---- pre-convert+transpose weights: Wt[l'][n][k] = W[l][k][n] (bf16), l' = branch*3+l ----
__global__ void convert_w_kernel(const float* __restrict__ sc_W, const float* __restrict__ fc_W,
                                 u16* __restrict__ Wt) {
    int idx = blockIdx.x * 256 + threadIdx.x;  // 6*16384 total
    if (idx >= 6 * 16384) return;
    int lp = idx >> 14;
    int r = idx & 16383;
    int n = r >> 7, k = r & 127;
    const float* W = (lp >= 3) ? fc_W : sc_W;
    int l = (lp >= 3) ? lp - 3 : lp;
    Wt[idx] = f2b(W[(size_t)l * 16384 + k * 128 + n]);
}

// ============================= MFMA GEMM (layer 0 only: fp32 input, LDS-staged) =============================
__global__ __launch_bounds__(256) void gemm2_kernel(
        const void* __restrict__ A_sc, const void* __restrict__ A_fc, int a_fp32,
        const u16* __restrict__ Wt, int layer,
        const float* __restrict__ d_sc, const float* __restrict__ d_fc,
        u16* __restrict__ H_sc, u16* __restrict__ H_fc) {
    int branch = blockIdx.x >= GB;
    int blk = branch ? blockIdx.x - GB : blockIdx.x;
    const void* A = branch ? A_fc : A_sc;
    const float* dis = branch ? d_fc : d_sc;
    u16* H = branch ? H_fc : H_sc;
    const u16* W = Wt + (((size_t)branch * 3 + layer) << 14);

    __shared__ u16 Alds[64 * 136];   // rows padded to 136 u16 (272 B)
    __shared__ u16 Wlds[128 * 136];  // Wt rows: n-major, k contiguous
    const int tid = threadIdx.x;
    const int row0 = blk * 64;

    if (a_fp32) {
        const float* Af = (const float*)A;
#pragma unroll
        for (int i = 0; i < 8; ++i) {
            int idx = tid + i * 256;
            int r = idx >> 5, f = idx & 31;
            int grow = row0 + r;
            float4 v = (grow < N_NODES) ? *(const float4*)&Af[(size_t)grow * 128 + f * 4]
                                        : make_float4(0.f, 0.f, 0.f, 0.f);
            ushort4 o;
            o.x = f2b(v.x); o.y = f2b(v.y); o.z = f2b(v.z); o.w = f2b(v.w);
            *(ushort4*)&Alds[r * 136 + f * 4] = o;
        }
    } else {
        const u16* Ab = (const u16*)A;
#pragma unroll
        for (int i = 0; i < 4; ++i) {
            int idx = tid + i * 256;
            int r = idx >> 4, f = idx & 15;
            int grow = row0 + r;
            u16x8 v = {};
            if (grow < N_NODES) v = *(const u16x8*)&Ab[(size_t)grow * 128 + f * 8];
            *(u16x8*)&Alds[r * 136 + f * 8] = v;
        }
    }
#pragma unroll
    for (int i = 0; i < 8; ++i) {
        int idx = tid + i * 256;
        int n = idx >> 4, f = idx & 15;
        *(u16x8*)&Wlds[n * 136 + f * 8] = *(const u16x8*)&W[n * 128 + f * 8];
    }
    __syncthreads();

    const int wv = tid >> 6;
    const int lane = tid & 63;
    const int m = lane & 15;       // row (A) / col (B) within 16-tile
    const int quad = lane >> 4;    // k-subchunk

    bf16x8 af[4];
#pragma unroll
    for (int kt = 0; kt < 4; ++kt)
        af[kt] = *(const bf16x8*)&Alds[(wv * 16 + m) * 136 + kt * 32 + quad * 8];

    f32x4 acc[8];
#pragma unroll
    for (int ct = 0; ct < 8; ++ct) { acc[ct][0] = 0.f; acc[ct][1] = 0.f; acc[ct][2] = 0.f; acc[ct][3] = 0.f; }

#pragma unroll
    for (int ct = 0; ct < 8; ++ct) {
#pragma unroll
        for (int kt = 0; kt < 4; ++kt) {
            bf16x8 bf = *(const bf16x8*)&Wlds[(ct * 16 + m) * 136 + kt * 32 + quad * 8];
            acc[ct] = __builtin_amdgcn_mfma_f32_16x16x32_bf16(af[kt], bf, acc[ct], 0, 0, 0);
        }
    }

    float4 dv = *(const float4*)&dis[row0 + wv * 16 + quad * 4];  // ws-padded, OOB-safe
#pragma unroll
    for (int ct = 0; ct < 8; ++ct) {
        acc[ct][0] *= dv.x; acc[ct][1] *= dv.y; acc[ct][2] *= dv.z; acc[ct][3] *= dv.w;
    }

#pragma unroll
    for (int ct = 0; ct < 8; ++ct)
#pragma unroll
        for (int r = 0; r < 4; ++r)
            Alds[(wv * 16 + quad * 4 + r) * 136 + ct * 16 + m] = f2b(acc[ct][r]);
    __syncthreads();
#pragma unroll
    for (int i = 0; i < 4; ++i) {
        int idx = i * 64 + lane;
        int r = idx >> 4, f = idx & 15;
        int grow = row0 + wv * 16 + r;
        if (grow < N_NODES)
            *(u16x8*)&H[(size_t)grow * 128 + f * 8] = *(const u16x8*)&Alds[(wv * 16 + r) * 136 + f * 8];
    }
}

// ============================= fused gather(l) + gemm(l+1)  (r4-v1: dual-branch, 4-wave blocks) =============================
// Measured A/B across r4/r5/r6: dual-branch 4-wave fgg = 186 us/layer beats
// per-branch split (202.8) and 16-wave (192): 2x blocks in flight mix the
// gather/gemm phases so the fetch pipe never drains; smallest barrier scope
// minimizes coupling stalls. L2-locality from splitting measured null
// (FETCH halved exactly proportionally, r6).
__global__ __launch_bounds__(256, 6) void fgg_kernel(
        const u16* __restrict__ h_sc_in, const u16* __restrict__ h_fc_in,
        const int* __restrict__ srcs_sc, const int* __restrict__ srcs_fc,
        const int* __restrict__ off_sc, const int* __restrict__ off_fc,
        const float* __restrict__ d_sc, const float* __restrict__ d_fc,
        const float* __restrict__ b_sc, const float* __restrict__ b_fc,  // bias of layer l (pre-offset)
        const u16* __restrict__ Wt, int wl,                               // weight layer l+1
        u16* __restrict__ h_sc_out, u16* __restrict__ h_fc_out) {
    int bb = blockIdx.x;
    int branch = bb >= FGG_NB;
    if (branch) bb -= FGG_NB;
    const u16* h    = branch ? h_fc_in : h_sc_in;
    const int* srcs = branch ? srcs_fc : srcs_sc;
    const int* offs = branch ? off_fc : off_sc;
    const float* dis = branch ? d_fc : d_sc;
    const float* bias = branch ? b_fc : b_sc;
    u16* hout = branch ? h_fc_out : h_sc_out;
    const u16* W = Wt + (((size_t)branch * 3 + wl) << 14);

    __shared__ u16 xt[16 * 136];   // x tile; reused as epilogue transpose buffer

    const int tid = threadIdx.x;
    const int wv = tid >> 6;
    const int lane = tid & 63;
    const int quarter = lane >> 4;
    const int c = (lane & 15) * 8;
    const int node0 = bb * 16;     // N_NODES = 6250*16 exactly -> no OOB

    // ---- gather phase: 4 sequential nodes per wave ----
    for (int nn = 0; nn < 4; ++nn) {
        int node = node0 + wv * 4 + nn;
        int beg = offs[node], end = offs[node + 1];
        u16x8 hv = *(const u16x8*)&h[(size_t)node * 128 + c];
        float dn = dis[node];
        float acc[8] = {0.f, 0.f, 0.f, 0.f, 0.f, 0.f, 0.f, 0.f};
        for (int j = beg + quarter; j < end; j += 16) {
            int o1 = (j + 4  < end) ? 4  : 0;
            int o2 = (j + 8  < end) ? 8  : 0;
            int o3 = (j + 12 < end) ? 12 : 0;
            float m1 = o1 ? 1.f : 0.f;
            float m2 = o2 ? 1.f : 0.f;
            float m3 = o3 ? 1.f : 0.f;
            int s0 = __builtin_nontemporal_load(&srcs[j]);
            int s1 = __builtin_nontemporal_load(&srcs[j + o1]);
            int s2 = __builtin_nontemporal_load(&srcs[j + o2]);
            int s3 = __builtin_nontemporal_load(&srcs[j + o3]);
            u16x8 v0 = *(const u16x8*)&h[(size_t)s0 * 128 + c];
            u16x8 v1 = *(const u16x8*)&h[(size_t)s1 * 128 + c];
            u16x8 v2 = *(const u16x8*)&h[(size_t)s2 * 128 + c];
            u16x8 v3 = *(const u16x8*)&h[(size_t)s3 * 128 + c];
#pragma unroll
            for (int t = 0; t < 8; ++t) {
                acc[t] += b2f(v0[t]);
                acc[t] = fmaf(m1, b2f(v1[t]), acc[t]);
                acc[t] = fmaf(m2, b2f(v2[t]), acc[t]);
                acc[t] = fmaf(m3, b2f(v3[t]), acc[t]);
            }
        }
#pragma unroll
        for (int t = 0; t < 8; ++t) {
            acc[t] += __shfl_xor(acc[t], 16);
            acc[t] += __shfl_xor(acc[t], 32);
        }
        if (quarter == 0) {
            float4 b0 = *(const float4*)&bias[c];
            float4 b1 = *(const float4*)&bias[c + 4];
            float bv[8] = {b0.x, b0.y, b0.z, b0.w, b1.x, b1.y, b1.z, b1.w};
            u16x8 o;
#pragma unroll
            for (int t = 0; t < 8; ++t)
                o[t] = f2b(fmaxf(dn * (acc[t] + b2f(hv[t])) + bv[t], 0.f));
            *(u16x8*)&xt[(wv * 4 + nn) * 136 + c] = o;
        }
    }
    __syncthreads();

    // ---- GEMM phase: 16x128 tile, wave wv computes cols [wv*32, wv*32+32) ----
    const int m = lane & 15;
    const int quad = lane >> 4;
    bf16x8 af[4];
#pragma unroll
    for (int kt = 0; kt < 4; ++kt)
        af[kt] = *(const bf16x8*)&xt[m * 136 + kt * 32 + quad * 8];

    f32x4 acc2[2];
    acc2[0][0] = 0.f; acc2[0][1] = 0.f; acc2[0][2] = 0.f; acc2[0][3] = 0.f;
    acc2[1][0] = 0.f; acc2[1][1] = 0.f; acc2[1][2] = 0.f; acc2[1][3] = 0.f;
#pragma unroll
    for (int cc = 0; cc < 2; ++cc) {
        int ct = wv * 2 + cc;
        const u16* Wr = &W[(ct * 16 + m) * 128 + quad * 8];
#pragma unroll
        for (int kt = 0; kt < 4; ++kt) {
            bf16x8 bf = *(const bf16x8*)&Wr[kt * 32];
            acc2[cc] = __builtin_amdgcn_mfma_f32_16x16x32_bf16(af[kt], bf, acc2[cc], 0, 0, 0);
        }
    }
    float4 dv = *(const float4*)&dis[node0 + quad * 4];
    __syncthreads();   // all af reads done -> xt reusable as epilogue buffer
#pragma unroll
    for (int cc = 0; cc < 2; ++cc) {
        float dm[4] = {dv.x, dv.y, dv.z, dv.w};
#pragma unroll
        for (int r = 0; r < 4; ++r)
            xt[(quad * 4 + r) * 136 + (wv * 2 + cc) * 16 + m] = f2b(acc2[cc][r] * dm[r]);
    }
    __syncthreads();
    // coalesced store: 16 rows x 128 cols = 256 u16x8, one per thread
    {
        int r = tid >> 4, f = tid & 15;
        *(u16x8*)&hout[(size_t)(node0 + r) * 128 + f * 8] = *(const u16x8*)&xt[r * 136 + f * 8];
    }
}

// ============================= GCN aggregation (final layer; dual-branch dispatch) =============================
__global__ __launch_bounds__(256, 8) void gather2_kernel(
        const u16* __restrict__ h_sc, const u16* __restrict__ h_fc,
        const int* __restrict__ srcs_sc, const int* __restrict__ srcs_fc,
        const int* __restrict__ off_sc, const int* __restrict__ off_fc,
        const float* __restrict__ d_sc, const float* __restrict__ d_fc,
        const float* __restrict__ b_sc, const float* __restrict__ b_fc,
        u16* __restrict__ x_sc, u16* __restrict__ x_fc) {
    int bb = blockIdx.x;
    int branch = bb >= GAT_NB;
    if (branch) bb -= GAT_NB;
    const u16* h    = branch ? h_fc : h_sc;
    const int* srcs = branch ? srcs_fc : srcs_sc;
    const int* offs = branch ? off_fc : off_sc;
    const float* dis = branch ? d_fc : d_sc;
    const float* bias = branch ? b_fc : b_sc;
    u16* xout = branch ? x_fc : x_sc;

    int node = bb * 4 + (threadIdx.x >> 6);
    int lane = threadIdx.x & 63;
    int quarter = lane >> 4;
    int c = (lane & 15) * 8;
    int beg = offs[node], end = offs[node + 1];

    u16x8 hv = *(const u16x8*)&h[(size_t)node * 128 + c];
    float dn = dis[node];

    float acc[8] = {0.f, 0.f, 0.f, 0.f, 0.f, 0.f, 0.f, 0.f};
    for (int j = beg + quarter; j < end; j += 16) {
        int o1 = (j + 4  < end) ? 4  : 0;
        int o2 = (j + 8  < end) ? 8  : 0;
        int o3 = (j + 12 < end) ? 12 : 0;
        float m1 = o1 ? 1.f : 0.f;
        float m2 = o2 ? 1.f : 0.f;
        float m3 = o3 ? 1.f : 0.f;
        int s0 = __builtin_nontemporal_load(&srcs[j]);
        int s1 = __builtin_nontemporal_load(&srcs[j + o1]);
        int s2 = __builtin_nontemporal_load(&srcs[j + o2]);
        int s3 = __builtin_nontemporal_load(&srcs[j + o3]);
        u16x8 v0 = *(const u16x8*)&h[(size_t)s0 * 128 + c];
        u16x8 v1 = *(const u16x8*)&h[(size_t)s1 * 128 + c];
        u16x8 v2 = *(const u16x8*)&h[(size_t)s2 * 128 + c];
        u16x8 v3 = *(const u16x8*)&h[(size_t)s3 * 128 + c];
#pragma unroll
        for (int t = 0; t < 8; ++t) {
            acc[t] += b2f(v0[t]);
            acc[t] = fmaf(m1, b2f(v1[t]), acc[t]);
            acc[t] = fmaf(m2, b2f(v2[t]), acc[t]);
            acc[t] = fmaf(m3, b2f(v3[t]), acc[t]);
        }
    }
#pragma unroll
    for (int t = 0; t < 8; ++t) {
        acc[t] += __shfl_xor(acc[t], 16);
        acc[t] += __shfl_xor(acc[t], 32);
    }
    if (quarter == 0) {
        float4 b0 = *(const float4*)&bias[c];
        float4 b1 = *(const float4*)&bias[c + 4];
        float bv[8] = {b0.x, b0.y, b0.z, b0.w, b1.x, b1.y, b1.z, b1.w};
        u16x8 o;
#pragma unroll
        for (int t = 0; t < 8; ++t)
            o[t] = f2b(fmaxf(dn * (acc[t] + b2f(hv[t])) + bv[t], 0.f));
        __builtin_nontemporal_store(o, (u16x8*)&xout[(size_t)node * 128 + c]);
    }
}

// ============================= pooling (batch is sorted; x is bf16, fp32 accumulate) =============================
__global__ __launch_bounds__(128) void pool2_kernel(const u16* __restrict__ x_sc,
                                                    const u16* __restrict__ x_fc,
                                                    const int* __restrict__ batch,
                                                    float* __restrict__ g_sc,
                                                    float* __restrict__ g_fc) {
    int b = blockIdx.x;
    const u16* x = (b >= PB) ? x_fc : x_sc;
    float* g     = (b >= PB) ? g_fc : g_sc;
    int blk = (b >= PB) ? b - PB : b;
    int c = threadIdx.x;
    int start = blk * 64;
    if (start >= N_NODES) return;
    int endn = min(start + 64, N_NODES);
    float acc = 0.f;
    int cur = batch[start];
    for (int i = start; i < endn; ++i) {
        int bb = batch[i];
        if (bb != cur) {
            atomicAdd(&g[(size_t)cur * 128 + c], acc);
            acc = 0.f;
            cur = bb;
        }
        acc += b2f(x[(size_t)i * 128 + c]);
    }
    atomicAdd(&g[(size_t)cur * 128 + c], acc);
}

// ============================= row L2-normalize =============================
__global__ __launch_bounds__(64) void normalize_kernel(const float* __restrict__ g_sc,
                                                       const float* __restrict__ g_fc,
                                                       float* __restrict__ n_sc,
                                                       float* __restrict__ n_fc) {
    int r = blockIdx.x & 255;
    const float* g = (blockIdx.x < 256) ? g_sc : g_fc;
    float* o = (blockIdx.x < 256) ? n_sc : n_fc;
    int c = threadIdx.x;
    float v0 = g[r * 128 + c], v1 = g[r * 128 + c + 64];
    float ss = v0 * v0 + v1 * v1;
#pragma unroll
    for (int off = 32; off; off >>= 1) ss += __shfl_xor(ss, off);
    float inv = 1.0f / fmaxf(sqrtf(ss), 1e-12f);
    o[r * 128 + c] = v0 * inv;
    o[r * 128 + c + 64] = v1 * inv;
}

// ============================= classifier head =============================
__global__ __launch_bounds__(128) void head_kernel(const float* __restrict__ g_sc,
                                                   const float* __restrict__ g_fc,
                                                   const float* __restrict__ W1,
                                                   const float* __restrict__ b1,
                                                   const float* __restrict__ W2,
                                                   const float* __restrict__ b2,
                                                   float* __restrict__ out) {
    __shared__ float cat[256];
    __shared__ float red[4];
    int i = blockIdx.x, c = threadIdx.x;
    cat[c] = g_sc[i * 128 + c];
    cat[128 + c] = g_fc[i * 128 + c];
    __syncthreads();
    float acc = b1[c];
    for (int k = 0; k < 256; ++k) acc += cat[k] * W1[k * 128 + c];
    float z = fmaxf(acc, 0.f);
    float l0 = z * W2[c * 2 + 0];
    float l1 = z * W2[c * 2 + 1];
#pragma unroll
    for (int off = 32; off; off >>= 1) {
        l0 += __shfl_xor(l0, off);
        l1 += __shfl_xor(l1, off);
    }
    if ((c & 63) == 0) {
        red[(c >> 6) * 2 + 0] = l0;
        red[(c >> 6) * 2 + 1] = l1;
    }
    __syncthreads();
    if (c == 0) {
        float L0 = red[0] + red[2] + b2[0];
        float L1 = red[1] + red[3] + b2[1];
        float m = fmaxf(L0, L1);
        float lse = m + logf(expf(L0 - m) + expf(L1 - m));
        out[i * 2 + 0] = L0 - lse;
        out[i * 2 + 1] = L1 - lse;
    }
}

// ============================= contrastive loss =============================
__global__ __launch_bounds__(256) void contrast_kernel(const float* __restrict__ n_sc,
                                                       const float* __restrict__ n_fc,
                                                       float* __restrict__ loss_acc) {
    __shared__ float arow[128];
    __shared__ float redm[4];
    __shared__ float reds[4];
    __shared__ float diag_s;
    int b = blockIdx.x;
    int i = b & 255;
    bool which = b >= 256;
    const float* A  = which ? n_fc : n_sc;
    const float* B1 = which ? n_sc : n_fc;
    const float* B2 = which ? n_fc : n_sc;
    int j = threadIdx.x;
    if (j < 128) arow[j] = A[i * 128 + j];
    __syncthreads();
    float d1 = 0.f, d2 = 0.f;
    for (int k = 0; k < 128; ++k) {
        float a = arow[k];
        d1 += a * B1[(size_t)j * 128 + k];
        d2 += a * B2[(size_t)j * 128 + k];
    }
    const float t = 2.0f;  // 1/TEMPERATURE
    float v1 = t * d1;
    float v2 = (j == i) ? 0.0f : 0.8f * t * d2;
    if (j == i) diag_s = v1;
    float m = fmaxf(v1, v2);
#pragma unroll
    for (int off = 32; off; off >>= 1) m = fmaxf(m, __shfl_xor(m, off));
    if ((j & 63) == 0) redm[j >> 6] = m;
    __syncthreads();
    m = fmaxf(fmaxf(redm[0], redm[1]), fmaxf(redm[2], redm[3]));
    float s = expf(v1 - m) + expf(v2 - m);
#pragma unroll
    for (int off = 32; off; off >>= 1) s += __shfl_xor(s, off);
    if ((j & 63) == 0) reds[j >> 6] = s;
    __syncthreads();
    if (j == 0) {
        float S = reds[0] + reds[1] + reds[2] + reds[3];
        float lse = m + logf(S);
        atomicAdd(loss_acc, lse - diag_s);
    }
}

__global__ void final_add(float* __restrict__ out, const float* __restrict__ loss) {
    int t = threadIdx.x;
    if (t < 512) out[t] += loss[0] * (1.0f / 512.0f);
}

// ============================= launch =============================

extern "C" void kernel_launch(void* const* d_in, const int* in_sizes, int n_in,
                              void* d_out, int out_size, void* d_ws, size_t ws_size,
                              hipStream_t stream) {
    const float* sc_x  = (const float*)d_in[0];
    const float* fc_x  = (const float*)d_in[1];
    const int*   sc_ei = (const int*)d_in[2];
    const int*   fc_ei = (const int*)d_in[3];
    const int*   batch = (const int*)d_in[4];
    const float* sc_W  = (const float*)d_in[5];
    const float* sc_b  = (const float*)d_in[6];
    const float* fc_W  = (const float*)d_in[7];
    const float* fc_b  = (const float*)d_in[8];
    const float* fc1_W = (const float*)d_in[9];
    const float* fc1_b = (const float*)d_in[10];
    const float* fc2_W = (const float*)d_in[11];
    const float* fc2_b = (const float*)d_in[12];
    float* out = (float*)d_out;

    const size_t NF = (size_t)N_NODES * HID;     // 12.8M elements
    const size_t TMPSZ = (size_t)NBUCK * BCAP;   // arena records per branch

    float* ws = (float*)d_ws;
    float* dis_sc = ws;                // N f32 (gemm epilogue float4 reads padded by dis_fc)
    float* dis_fc = dis_sc + N_NODES;  // N f32 (padded by g arrays after)
    float* g_sc  = dis_fc + N_NODES;   // g_sc,g_fc contiguous for one memset
    float* g_fc  = g_sc + NGRAPH * HID;
    float* n_sc  = g_fc + NGRAPH * HID;
    float* n_fc  = n_sc + NGRAPH * HID;
    float* lossp = n_fc + NGRAPH * HID;  // 1 (+pad)
    u16* h_sc    = (u16*)(lossp + 4);    // NF bf16
    u16* h_fc    = h_sc + NF;
    u16* x_sc    = h_fc + NF;            // NF bf16 (ping-pong buffer with h)
    u16* x_fc    = x_sc + NF;
    u16* Wtb     = x_fc + NF;            // 6*16384 bf16 (transposed weights)
    int* srcs_sc   = (int*)(Wtb + 6 * 16384);  // E
    int* srcs_fc   = srcs_sc + N_EDGES;
    u32* tmp_sc    = (u32*)(srcs_fc + N_EDGES);  // NBUCK*BCAP arena records
    u32* tmp_fc    = tmp_sc + TMPSZ;
    int* off_sc    = (int*)(tmp_fc + TMPSZ);     // N+1
    int* off_fc    = off_sc + (N_NODES + 1);
    int* bcur      = off_fc + (N_NODES + 1);     // 2*NBUCK
    int* bktoff    = bcur + 2 * NBUCK;           // 2*(NBUCK+1)
    (void)ws_size; (void)n_in; (void)in_sizes; (void)out_size;

    // ---- CSR build (single edge pass into arenas) ----
    bcur_init_kernel<<<1, 512, 0, stream>>>(bcur);
    buildA_kernel<<<2 * ABLK, 256, 0, stream>>>(sc_ei, fc_ei, bcur, tmp_sc, tmp_fc);
    arena_scan_kernel<<<1, 256, 0, stream>>>(bcur, bktoff);
    bucket_fin_kernel<<<2 * NBUCK, 256, 0, stream>>>(tmp_sc, tmp_fc, bcur, bktoff,
                                                     off_sc, off_fc, dis_sc, dis_fc,
                                                     srcs_sc, srcs_fc);
    convert_w_kernel<<<(6 * 16384 + 255) / 256, 256, 0, stream>>>(sc_W, fc_W, Wtb);

    // ---- layer pipeline: gemm(l0) -> fgg(l0) -> fgg(l1) -> gather(l2), all dual-branch ----
    // buffers ping-pong: h (h0) -> x (h1) -> h (h2) -> x (x3, pooled)
    gemm2_kernel<<<2 * GB, 256, 0, stream>>>(sc_x, fc_x, 1, Wtb, 0,
                                             dis_sc, dis_fc, h_sc, h_fc);
    fgg_kernel<<<2 * FGG_NB, 256, 0, stream>>>(
        h_sc, h_fc, srcs_sc, srcs_fc, off_sc, off_fc, dis_sc, dis_fc,
        sc_b, fc_b, Wtb, 1, x_sc, x_fc);
    fgg_kernel<<<2 * FGG_NB, 256, 0, stream>>>(
        x_sc, x_fc, srcs_sc, srcs_fc, off_sc, off_fc, dis_sc, dis_fc,
        sc_b + HID, fc_b + HID, Wtb, 2, h_sc, h_fc);
    gather2_kernel<<<2 * GAT_NB, 256, 0, stream>>>(
        h_sc, h_fc, srcs_sc, srcs_fc, off_sc, off_fc,
        dis_sc, dis_fc, sc_b + 2 * HID, fc_b + 2 * HID, x_sc, x_fc);

    // ---- pooling ----
    hipMemsetAsync(g_sc, 0, 2 * NGRAPH * HID * sizeof(float), stream);
    pool2_kernel<<<2 * PB, 128, 0, stream>>>(x_sc, x_fc, batch, g_sc, g_fc);

    // ---- head + contrastive ----
    normalize_kernel<<<512, 64, 0, stream>>>(g_sc, g_fc, n_sc, n_fc);
    head_kernel<<<NGRAPH, 128, 0, stream>>>(g_sc, g_fc, fc1_W, fc1_b, fc2_W, fc2_b, out);
    hipMemsetAsync(lossp, 0, sizeof(float), stream);
    contrast_kernel<<<512, 256, 0, stream>>>(n_sc, n_fc, lossp);
    final_add<<<1, 512, 0, stream>>>(out, lossp);
}

// Round 8
// 728.779 us; speedup vs baseline: 1.2233x; 1.1516x over previous
//
#include <hip/hip_runtime.h>
#include <math.h>

#define N_NODES 100000
#define N_EDGES 1600000
#define HID     128
#define NGRAPH  256
#define GB      ((N_NODES + 63) / 64)               // 1563 gemm blocks per branch
#define GAT_NB  (N_NODES / 4)                       // 25000 gather blocks per branch
#define FGG_NB  (N_NODES / 16)                      // 6250 fused gather+gemm blocks per branch
#define PB      ((N_NODES + 63) / 64)               // 1563 pool blocks per branch
#define NBUCK   ((N_NODES + 511) / 512)             // 196 buckets (512 nodes each)
#define BCAP    12288                               // arena capacity/bucket (mean 8192 + 45 sd)
#define AVPT    16
#define ABLK    ((N_EDGES + 256 * AVPT - 1) / (256 * AVPT))  // 391 edge-sweep blocks per branch

typedef unsigned short u16;
typedef unsigned char  u8;
typedef unsigned int   u32;
typedef __attribute__((ext_vector_type(8))) short    bf16x8;
typedef __attribute__((ext_vector_type(4))) float    f32x4;
typedef __attribute__((ext_vector_type(8))) unsigned short u16x8;

__device__ inline float b2f(u16 u) {
    union { unsigned int i; float f; } x; x.i = ((unsigned int)u) << 16; return x.f;
}
__device__ inline u16 f2b(float f) {
    union { float f; unsigned int i; } x; x.f = f;
    unsigned int r = x.i + 0x7fff + ((x.i >> 16) & 1);   // round-to-nearest-even
    return (u16)(r >> 16);
}

// ============================= CSR build (arena single-pass, no per-node global atomics) =============================

__global__ void bcur_init_kernel(int* __restrict__ bcur) {
    int t = threadIdx.x;  // one block of 512 covers 2*NBUCK=392
    if (t >= 2 * NBUCK) return;
    int k = (t >= NBUCK) ? t - NBUCK : t;
    bcur[t] = k * BCAP;
}

__global__ __launch_bounds__(256) void buildA_kernel(
        const int* __restrict__ sc_ei, const int* __restrict__ fc_ei,
        int* __restrict__ bcur,
        u32* __restrict__ tmp_sc, u32* __restrict__ tmp_fc) {
    int b = blockIdx.x;
    int branch = b >= ABLK;
    int blk = branch ? b - ABLK : b;
    const int* ei = branch ? fc_ei : sc_ei;
    u32* tmp      = branch ? tmp_fc : tmp_sc;
    int* bc       = bcur + (branch ? NBUCK : 0);

    __shared__ int hist[NBUCK];
    __shared__ int cur[NBUCK];
    int tid = threadIdx.x;
    for (int i = tid; i < NBUCK; i += 256) hist[i] = 0;
    __syncthreads();

    int e0 = blk * (256 * AVPT) + tid;
    int ss[AVPT], dd[AVPT];
#pragma unroll
    for (int k = 0; k < AVPT; ++k) {
        int e = e0 + k * 256;
        bool v = e < N_EDGES;
        ss[k] = v ? ei[e] : 0;
        dd[k] = v ? ei[N_EDGES + e] : -1;
        if (v) atomicAdd(&hist[dd[k] >> 9], 1);
    }
    __syncthreads();
    for (int i = tid; i < NBUCK; i += 256) {
        int c = hist[i];
        cur[i] = c ? atomicAdd(&bc[i], c) : 0;   // arena slot (bucket*BCAP-based)
    }
    __syncthreads();
#pragma unroll
    for (int k = 0; k < AVPT; ++k) {
        if (dd[k] >= 0) {
            int pos = atomicAdd(&cur[dd[k] >> 9], 1);
            tmp[pos] = ((u32)ss[k] << 9) | (u32)(dd[k] & 511);
        }
    }
}

// post-buildA: counts = bcur_final - bucket*BCAP; exclusive scan -> CSR bases
__global__ __launch_bounds__(256) void arena_scan_kernel(
        const int* __restrict__ bcur, int* __restrict__ bktoff) {
    __shared__ int lds[2][256];
    int tid = threadIdx.x;
    int v0 = (tid < NBUCK) ? bcur[tid] - tid * BCAP : 0;
    int v1 = (tid < NBUCK) ? bcur[NBUCK + tid] - tid * BCAP : 0;
    lds[0][tid] = v0;
    lds[1][tid] = v1;
    __syncthreads();
    for (int off = 1; off < 256; off <<= 1) {
        int t0 = (tid >= off) ? lds[0][tid - off] : 0;
        int t1 = (tid >= off) ? lds[1][tid - off] : 0;
        __syncthreads();
        lds[0][tid] += t0;
        lds[1][tid] += t1;
        __syncthreads();
    }
    if (tid < NBUCK) {
        bktoff[tid] = lds[0][tid] - v0;               // exclusive
        bktoff[(NBUCK + 1) + tid] = lds[1][tid] - v1;
    }
    if (tid == 0) {
        bktoff[NBUCK] = N_EDGES;
        bktoff[(NBUCK + 1) + NBUCK] = N_EDGES;
    }
}

// per-bucket finalize: LDS degree count -> off[]+dis[], LDS-cursor scatter -> srcs
__global__ __launch_bounds__(256) void bucket_fin_kernel(
        const u32* __restrict__ tmp_sc, const u32* __restrict__ tmp_fc,
        const int* __restrict__ bcur, const int* __restrict__ bktoff,
        int* __restrict__ off_sc, int* __restrict__ off_fc,
        float* __restrict__ d_sc, float* __restrict__ d_fc,
        int* __restrict__ srcs_sc, int* __restrict__ srcs_fc) {
    int b = blockIdx.x;
    int branch = b >= NBUCK;
    int bucket = branch ? b - NBUCK : b;
    const u32* tmp = branch ? tmp_fc : tmp_sc;
    const int* bo  = bktoff + (branch ? (NBUCK + 1) : 0);
    int* off   = branch ? off_fc : off_sc;
    float* dis = branch ? d_fc : d_sc;
    int* srcs  = branch ? srcs_fc : srcs_sc;
    int node0 = bucket << 9;
    int beg_t = bucket * BCAP;                       // arena range
    int end_t = bcur[branch * NBUCK + bucket];
    int csr0  = bo[bucket];                          // CSR base of this bucket

    __shared__ int cnt[512];
    __shared__ int cur[512];
    __shared__ int psum[256];
    int tid = threadIdx.x;
    cnt[2 * tid] = 0; cnt[2 * tid + 1] = 0;
    __syncthreads();
    for (int r = beg_t + tid; r < end_t; r += 256)
        atomicAdd(&cnt[tmp[r] & 511], 1);
    __syncthreads();
    int c0 = cnt[2 * tid], c1 = cnt[2 * tid + 1];
    int s = c0 + c1;
    psum[tid] = s;
    __syncthreads();
    for (int o = 1; o < 256; o <<= 1) {
        int t = (tid >= o) ? psum[tid - o] : 0;
        __syncthreads();
        psum[tid] += t;
        __syncthreads();
    }
    int base = csr0 + psum[tid] - s;   // exclusive start of node 2*tid
    int n0 = node0 + 2 * tid, n1 = node0 + 2 * tid + 1;
    if (n0 < N_NODES) { off[n0] = base;      dis[n0] = rsqrtf((float)c0 + 1.0f); }
    if (n1 < N_NODES) { off[n1] = base + c0; dis[n1] = rsqrtf((float)c1 + 1.0f); }
    cur[2 * tid] = base;
    cur[2 * tid + 1] = base + c0;
    __syncthreads();
    for (int r = beg_t + tid; r < end_t; r += 256) {
        u32 rec = tmp[r];
        int pos = atomicAdd(&cur[rec & 511], 1);
        srcs[pos] = rec >> 9;
    }
    if (b == 0 && tid == 0) { off_sc[N_NODES] = N_EDGES; off_fc[N_NODES] = N_EDGES; }
}

// ---- pre-convert+transpose weights: Wt[l'][n][k] = W[l][k][n] (bf16), l' = branch*3+l ----
__global__ void convert_w_kernel(const float* __restrict__ sc_W, const float* __restrict__ fc_W,
                                 u16* __restrict__ Wt) {
    int idx = blockIdx.x * 256 + threadIdx.x;  // 6*16384 total
    if (idx >= 6 * 16384) return;
    int lp = idx >> 14;
    int r = idx & 16383;
    int n = r >> 7, k = r & 127;
    const float* W = (lp >= 3) ? fc_W : sc_W;
    int l = (lp >= 3) ? lp - 3 : lp;
    Wt[idx] = f2b(W[(size_t)l * 16384 + k * 128 + n]);
}

// ============================= MFMA GEMM (layer 0: fp32 input, LDS-staged; fp8 h output) =============================
// r8: h (pre-gather activations) stored as fp8 e4m3. Each edge-gather then
// reads ONE 128B cache line instead of two -- the gather path is line-service
// bound (3 probes, r1/r5/r6), so this is the only remaining lever. All
// accumulation stays fp32; GEMMs stay bf16 MFMA; only h storage quantized.
__global__ __launch_bounds__(256) void gemm2_kernel(
        const void* __restrict__ A_sc, const void* __restrict__ A_fc, int a_fp32,
        const u16* __restrict__ Wt, int layer,
        const float* __restrict__ d_sc, const float* __restrict__ d_fc,
        u8* __restrict__ H_sc, u8* __restrict__ H_fc) {
    int branch = blockIdx.x >= GB;
    int blk = branch ? blockIdx.x - GB : blockIdx.x;
    const void* A = branch ? A_fc : A_sc;
    const float* dis = branch ? d_fc : d_sc;
    u8* H = branch ? H_fc : H_sc;
    const u16* W = Wt + (((size_t)branch * 3 + layer) << 14);

    __shared__ u16 Alds[64 * 136];   // rows padded to 136 u16 (272 B)
    __shared__ u16 Wlds[128 * 136];  // Wt rows: n-major, k contiguous
    const int tid = threadIdx.x;
    const int row0 = blk * 64;

    if (a_fp32) {
        const float* Af = (const float*)A;
#pragma unroll
        for (int i = 0; i < 8; ++i) {
            int idx = tid + i * 256;
            int r = idx >> 5, f = idx & 31;
            int grow = row0 + r;
            float4 v = (grow < N_NODES) ? *(const float4*)&Af[(size_t)grow * 128 + f * 4]
                                        : make_float4(0.f, 0.f, 0.f, 0.f);
            ushort4 o;
            o.x = f2b(v.x); o.y = f2b(v.y); o.z = f2b(v.z); o.w = f2b(v.w);
            *(ushort4*)&Alds[r * 136 + f * 4] = o;
        }
    } else {
        const u16* Ab = (const u16*)A;
#pragma unroll
        for (int i = 0; i < 4; ++i) {
            int idx = tid + i * 256;
            int r = idx >> 4, f = idx & 15;
            int grow = row0 + r;
            u16x8 v = {};
            if (grow < N_NODES) v = *(const u16x8*)&Ab[(size_t)grow * 128 + f * 8];
            *(u16x8*)&Alds[r * 136 + f * 8] = v;
        }
    }
#pragma unroll
    for (int i = 0; i < 8; ++i) {
        int idx = tid + i * 256;
        int n = idx >> 4, f = idx & 15;
        *(u16x8*)&Wlds[n * 136 + f * 8] = *(const u16x8*)&W[n * 128 + f * 8];
    }
    __syncthreads();

    const int wv = tid >> 6;
    const int lane = tid & 63;
    const int m = lane & 15;       // row (A) / col (B) within 16-tile
    const int quad = lane >> 4;    // k-subchunk

    bf16x8 af[4];
#pragma unroll
    for (int kt = 0; kt < 4; ++kt)
        af[kt] = *(const bf16x8*)&Alds[(wv * 16 + m) * 136 + kt * 32 + quad * 8];

    f32x4 acc[8];
#pragma unroll
    for (int ct = 0; ct < 8; ++ct) { acc[ct][0] = 0.f; acc[ct][1] = 0.f; acc[ct][2] = 0.f; acc[ct][3] = 0.f; }

#pragma unroll
    for (int ct = 0; ct < 8; ++ct) {
#pragma unroll
        for (int kt = 0; kt < 4; ++kt) {
            bf16x8 bf = *(const bf16x8*)&Wlds[(ct * 16 + m) * 136 + kt * 32 + quad * 8];
            acc[ct] = __builtin_amdgcn_mfma_f32_16x16x32_bf16(af[kt], bf, acc[ct], 0, 0, 0);
        }
    }

    float4 dv = *(const float4*)&dis[row0 + wv * 16 + quad * 4];  // ws-padded, OOB-safe
#pragma unroll
    for (int ct = 0; ct < 8; ++ct) {
        acc[ct][0] *= dv.x; acc[ct][1] *= dv.y; acc[ct][2] *= dv.z; acc[ct][3] *= dv.w;
    }

#pragma unroll
    for (int ct = 0; ct < 8; ++ct)
#pragma unroll
        for (int r = 0; r < 4; ++r)
            Alds[(wv * 16 + quad * 4 + r) * 136 + ct * 16 + m] = f2b(acc[ct][r]);
    __syncthreads();
#pragma unroll
    for (int i = 0; i < 4; ++i) {
        int idx = i * 64 + lane;
        int r = idx >> 4, f = idx & 15;
        int grow = row0 + wv * 16 + r;
        if (grow < N_NODES) {
            u16x8 t = *(const u16x8*)&Alds[(wv * 16 + r) * 136 + f * 8];
            int wa = __builtin_amdgcn_cvt_pk_fp8_f32(b2f(t[0]), b2f(t[1]), 0, false);
            wa     = __builtin_amdgcn_cvt_pk_fp8_f32(b2f(t[2]), b2f(t[3]), wa, true);
            int wb = __builtin_amdgcn_cvt_pk_fp8_f32(b2f(t[4]), b2f(t[5]), 0, false);
            wb     = __builtin_amdgcn_cvt_pk_fp8_f32(b2f(t[6]), b2f(t[7]), wb, true);
            *(uint2*)&H[(size_t)grow * 128 + f * 8] = make_uint2((u32)wa, (u32)wb);
        }
    }
}

// ============================= fused gather(l) + gemm(l+1)  (dual-branch, 4-wave blocks, fp8 h) =============================
__global__ __launch_bounds__(256, 6) void fgg_kernel(
        const u8* __restrict__ h_sc_in, const u8* __restrict__ h_fc_in,
        const int* __restrict__ srcs_sc, const int* __restrict__ srcs_fc,
        const int* __restrict__ off_sc, const int* __restrict__ off_fc,
        const float* __restrict__ d_sc, const float* __restrict__ d_fc,
        const float* __restrict__ b_sc, const float* __restrict__ b_fc,  // bias of layer l
        const u16* __restrict__ Wt, int wl,                               // weight layer l+1
        u8* __restrict__ h_sc_out, u8* __restrict__ h_fc_out) {
    int bb = blockIdx.x;
    int branch = bb >= FGG_NB;
    if (branch) bb -= FGG_NB;
    const u8* h     = branch ? h_fc_in : h_sc_in;
    const int* srcs = branch ? srcs_fc : srcs_sc;
    const int* offs = branch ? off_fc : off_sc;
    const float* dis = branch ? d_fc : d_sc;
    const float* bias = branch ? b_fc : b_sc;
    u8* hout = branch ? h_fc_out : h_sc_out;
    const u16* W = Wt + (((size_t)branch * 3 + wl) << 14);

    __shared__ u16 xt[16 * 136];   // x tile (bf16); reused as epilogue transpose buffer

    const int tid = threadIdx.x;
    const int wv = tid >> 6;
    const int lane = tid & 63;
    const int quarter = lane >> 4;
    const int c = (lane & 15) * 8;   // feature idx == byte offset (1 B/feature)
    const int node0 = bb * 16;       // N_NODES = 6250*16 exactly -> no OOB

    // ---- gather phase: 4 sequential nodes per wave; fp8 rows (1 line/edge) ----
    for (int nn = 0; nn < 4; ++nn) {
        int node = node0 + wv * 4 + nn;
        int beg = offs[node], end = offs[node + 1];
        uint2 hw = *(const uint2*)&h[(size_t)node * 128 + c];   // self row (fp8)
        float dn = dis[node];
        float acc[8] = {0.f, 0.f, 0.f, 0.f, 0.f, 0.f, 0.f, 0.f};
        for (int j = beg + quarter; j < end; j += 16) {
            int o1 = (j + 4  < end) ? 4  : 0;
            int o2 = (j + 8  < end) ? 8  : 0;
            int o3 = (j + 12 < end) ? 12 : 0;
            float m1 = o1 ? 1.f : 0.f;
            float m2 = o2 ? 1.f : 0.f;
            float m3 = o3 ? 1.f : 0.f;
            int s0 = __builtin_nontemporal_load(&srcs[j]);
            int s1 = __builtin_nontemporal_load(&srcs[j + o1]);
            int s2 = __builtin_nontemporal_load(&srcs[j + o2]);
            int s3 = __builtin_nontemporal_load(&srcs[j + o3]);
            uint2 v0 = *(const uint2*)&h[(size_t)s0 * 128 + c];
            uint2 v1 = *(const uint2*)&h[(size_t)s1 * 128 + c];
            uint2 v2 = *(const uint2*)&h[(size_t)s2 * 128 + c];
            uint2 v3 = *(const uint2*)&h[(size_t)s3 * 128 + c];
            {
                auto a0 = __builtin_amdgcn_cvt_pk_f32_fp8((int)v0.x, false);
                auto a1 = __builtin_amdgcn_cvt_pk_f32_fp8((int)v0.x, true);
                auto a2 = __builtin_amdgcn_cvt_pk_f32_fp8((int)v0.y, false);
                auto a3 = __builtin_amdgcn_cvt_pk_f32_fp8((int)v0.y, true);
                acc[0] += a0[0]; acc[1] += a0[1]; acc[2] += a1[0]; acc[3] += a1[1];
                acc[4] += a2[0]; acc[5] += a2[1]; acc[6] += a3[0]; acc[7] += a3[1];
            }
            {
                auto a0 = __builtin_amdgcn_cvt_pk_f32_fp8((int)v1.x, false);
                auto a1 = __builtin_amdgcn_cvt_pk_f32_fp8((int)v1.x, true);
                auto a2 = __builtin_amdgcn_cvt_pk_f32_fp8((int)v1.y, false);
                auto a3 = __builtin_amdgcn_cvt_pk_f32_fp8((int)v1.y, true);
                acc[0] = fmaf(m1, a0[0], acc[0]); acc[1] = fmaf(m1, a0[1], acc[1]);
                acc[2] = fmaf(m1, a1[0], acc[2]); acc[3] = fmaf(m1, a1[1], acc[3]);
                acc[4] = fmaf(m1, a2[0], acc[4]); acc[5] = fmaf(m1, a2[1], acc[5]);
                acc[6] = fmaf(m1, a3[0], acc[6]); acc[7] = fmaf(m1, a3[1], acc[7]);
            }
            {
                auto a0 = __builtin_amdgcn_cvt_pk_f32_fp8((int)v2.x, false);
                auto a1 = __builtin_amdgcn_cvt_pk_f32_fp8((int)v2.x, true);
                auto a2 = __builtin_amdgcn_cvt_pk_f32_fp8((int)v2.y, false);
                auto a3 = __builtin_amdgcn_cvt_pk_f32_fp8((int)v2.y, true);
                acc[0] = fmaf(m2, a0[0], acc[0]); acc[1] = fmaf(m2, a0[1], acc[1]);
                acc[2] = fmaf(m2, a1[0], acc[2]); acc[3] = fmaf(m2, a1[1], acc[3]);
                acc[4] = fmaf(m2, a2[0], acc[4]); acc[5] = fmaf(m2, a2[1], acc[5]);
                acc[6] = fmaf(m2, a3[0], acc[6]); acc[7] = fmaf(m2, a3[1], acc[7]);
            }
            {
                auto a0 = __builtin_amdgcn_cvt_pk_f32_fp8((int)v3.x, false);
                auto a1 = __builtin_amdgcn_cvt_pk_f32_fp8((int)v3.x, true);
                auto a2 = __builtin_amdgcn_cvt_pk_f32_fp8((int)v3.y, false);
                auto a3 = __builtin_amdgcn_cvt_pk_f32_fp8((int)v3.y, true);
                acc[0] = fmaf(m3, a0[0], acc[0]); acc[1] = fmaf(m3, a0[1], acc[1]);
                acc[2] = fmaf(m3, a1[0], acc[2]); acc[3] = fmaf(m3, a1[1], acc[3]);
                acc[4] = fmaf(m3, a2[0], acc[4]); acc[5] = fmaf(m3, a2[1], acc[5]);
                acc[6] = fmaf(m3, a3[0], acc[6]); acc[7] = fmaf(m3, a3[1], acc[7]);
            }
        }
#pragma unroll
        for (int t = 0; t < 8; ++t) {
            acc[t] += __shfl_xor(acc[t], 16);
            acc[t] += __shfl_xor(acc[t], 32);
        }
        if (quarter == 0) {
            auto q0 = __builtin_amdgcn_cvt_pk_f32_fp8((int)hw.x, false);
            auto q1 = __builtin_amdgcn_cvt_pk_f32_fp8((int)hw.x, true);
            auto q2 = __builtin_amdgcn_cvt_pk_f32_fp8((int)hw.y, false);
            auto q3 = __builtin_amdgcn_cvt_pk_f32_fp8((int)hw.y, true);
            float hvf[8] = {q0[0], q0[1], q1[0], q1[1], q2[0], q2[1], q3[0], q3[1]};
            float4 b0 = *(const float4*)&bias[c];
            float4 b1 = *(const float4*)&bias[c + 4];
            float bv[8] = {b0.x, b0.y, b0.z, b0.w, b1.x, b1.y, b1.z, b1.w};
            u16x8 o;
#pragma unroll
            for (int t = 0; t < 8; ++t)
                o[t] = f2b(fmaxf(dn * (acc[t] + hvf[t]) + bv[t], 0.f));
            *(u16x8*)&xt[(wv * 4 + nn) * 136 + c] = o;
        }
    }
    __syncthreads();

    // ---- GEMM phase: 16x128 tile, wave wv computes cols [wv*32, wv*32+32) ----
    const int m = lane & 15;
    const int quad = lane >> 4;
    bf16x8 af[4];
#pragma unroll
    for (int kt = 0; kt < 4; ++kt)
        af[kt] = *(const bf16x8*)&xt[m * 136 + kt * 32 + quad * 8];

    f32x4 acc2[2];
    acc2[0][0] = 0.f; acc2[0][1] = 0.f; acc2[0][2] = 0.f; acc2[0][3] = 0.f;
    acc2[1][0] = 0.f; acc2[1][1] = 0.f; acc2[1][2] = 0.f; acc2[1][3] = 0.f;
#pragma unroll
    for (int cc = 0; cc < 2; ++cc) {
        int ct = wv * 2 + cc;
        const u16* Wr = &W[(ct * 16 + m) * 128 + quad * 8];
#pragma unroll
        for (int kt = 0; kt < 4; ++kt) {
            bf16x8 bf = *(const bf16x8*)&Wr[kt * 32];
            acc2[cc] = __builtin_amdgcn_mfma_f32_16x16x32_bf16(af[kt], bf, acc2[cc], 0, 0, 0);
        }
    }
    float4 dv = *(const float4*)&dis[node0 + quad * 4];
    __syncthreads();   // all af reads done -> xt reusable as epilogue buffer
#pragma unroll
    for (int cc = 0; cc < 2; ++cc) {
        float dm[4] = {dv.x, dv.y, dv.z, dv.w};
#pragma unroll
        for (int r = 0; r < 4; ++r)
            xt[(quad * 4 + r) * 136 + (wv * 2 + cc) * 16 + m] = f2b(acc2[cc][r] * dm[r]);
    }
    __syncthreads();
    // fp8 store: 16 rows x 128 B = one uint2 per thread
    {
        int r = tid >> 4, f = tid & 15;
        u16x8 t = *(const u16x8*)&xt[r * 136 + f * 8];
        int wa = __builtin_amdgcn_cvt_pk_fp8_f32(b2f(t[0]), b2f(t[1]), 0, false);
        wa     = __builtin_amdgcn_cvt_pk_fp8_f32(b2f(t[2]), b2f(t[3]), wa, true);
        int wb = __builtin_amdgcn_cvt_pk_fp8_f32(b2f(t[4]), b2f(t[5]), 0, false);
        wb     = __builtin_amdgcn_cvt_pk_fp8_f32(b2f(t[6]), b2f(t[7]), wb, true);
        *(uint2*)&hout[(size_t)(node0 + r) * 128 + f * 8] = make_uint2((u32)wa, (u32)wb);
    }
}

// ============================= GCN aggregation (final layer; fp8 in, bf16 out for pool) =============================
__global__ __launch_bounds__(256, 8) void gather2_kernel(
        const u8* __restrict__ h_sc, const u8* __restrict__ h_fc,
        const int* __restrict__ srcs_sc, const int* __restrict__ srcs_fc,
        const int* __restrict__ off_sc, const int* __restrict__ off_fc,
        const float* __restrict__ d_sc, const float* __restrict__ d_fc,
        const float* __restrict__ b_sc, const float* __restrict__ b_fc,
        u16* __restrict__ x_sc, u16* __restrict__ x_fc) {
    int bb = blockIdx.x;
    int branch = bb >= GAT_NB;
    if (branch) bb -= GAT_NB;
    const u8* h     = branch ? h_fc : h_sc;
    const int* srcs = branch ? srcs_fc : srcs_sc;
    const int* offs = branch ? off_fc : off_sc;
    const float* dis = branch ? d_fc : d_sc;
    const float* bias = branch ? b_fc : b_sc;
    u16* xout = branch ? x_fc : x_sc;

    int node = bb * 4 + (threadIdx.x >> 6);
    int lane = threadIdx.x & 63;
    int quarter = lane >> 4;
    int c = (lane & 15) * 8;
    int beg = offs[node], end = offs[node + 1];

    uint2 hw = *(const uint2*)&h[(size_t)node * 128 + c];   // self row (fp8)
    float dn = dis[node];

    float acc[8] = {0.f, 0.f, 0.f, 0.f, 0.f, 0.f, 0.f, 0.f};
    for (int j = beg + quarter; j < end; j += 16) {
        int o1 = (j + 4  < end) ? 4  : 0;
        int o2 = (j + 8  < end) ? 8  : 0;
        int o3 = (j + 12 < end) ? 12 : 0;
        float m1 = o1 ? 1.f : 0.f;
        float m2 = o2 ? 1.f : 0.f;
        float m3 = o3 ? 1.f : 0.f;
        int s0 = __builtin_nontemporal_load(&srcs[j]);
        int s1 = __builtin_nontemporal_load(&srcs[j + o1]);
        int s2 = __builtin_nontemporal_load(&srcs[j + o2]);
        int s3 = __builtin_nontemporal_load(&srcs[j + o3]);
        uint2 v0 = *(const uint2*)&h[(size_t)s0 * 128 + c];
        uint2 v1 = *(const uint2*)&h[(size_t)s1 * 128 + c];
        uint2 v2 = *(const uint2*)&h[(size_t)s2 * 128 + c];
        uint2 v3 = *(const uint2*)&h[(size_t)s3 * 128 + c];
        {
            auto a0 = __builtin_amdgcn_cvt_pk_f32_fp8((int)v0.x, false);
            auto a1 = __builtin_amdgcn_cvt_pk_f32_fp8((int)v0.x, true);
            auto a2 = __builtin_amdgcn_cvt_pk_f32_fp8((int)v0.y, false);
            auto a3 = __builtin_amdgcn_cvt_pk_f32_fp8((int)v0.y, true);
            acc[0] += a0[0]; acc[1] += a0[1]; acc[2] += a1[0]; acc[3] += a1[1];
            acc[4] += a2[0]; acc[5] += a2[1]; acc[6] += a3[0]; acc[7] += a3[1];
        }
        {
            auto a0 = __builtin_amdgcn_cvt_pk_f32_fp8((int)v1.x, false);
            auto a1 = __builtin_amdgcn_cvt_pk_f32_fp8((int)v1.x, true);
            auto a2 = __builtin_amdgcn_cvt_pk_f32_fp8((int)v1.y, false);
            auto a3 = __builtin_amdgcn_cvt_pk_f32_fp8((int)v1.y, true);
            acc[0] = fmaf(m1, a0[0], acc[0]); acc[1] = fmaf(m1, a0[1], acc[1]);
            acc[2] = fmaf(m1, a1[0], acc[2]); acc[3] = fmaf(m1, a1[1], acc[3]);
            acc[4] = fmaf(m1, a2[0], acc[4]); acc[5] = fmaf(m1, a2[1], acc[5]);
            acc[6] = fmaf(m1, a3[0], acc[6]); acc[7] = fmaf(m1, a3[1], acc[7]);
        }
        {
            auto a0 = __builtin_amdgcn_cvt_pk_f32_fp8((int)v2.x, false);
            auto a1 = __builtin_amdgcn_cvt_pk_f32_fp8((int)v2.x, true);
            auto a2 = __builtin_amdgcn_cvt_pk_f32_fp8((int)v2.y, false);
            auto a3 = __builtin_amdgcn_cvt_pk_f32_fp8((int)v2.y, true);
            acc[0] = fmaf(m2, a0[0], acc[0]); acc[1] = fmaf(m2, a0[1], acc[1]);
            acc[2] = fmaf(m2, a1[0], acc[2]); acc[3] = fmaf(m2, a1[1], acc[3]);
            acc[4] = fmaf(m2, a2[0], acc[4]); acc[5] = fmaf(m2, a2[1], acc[5]);
            acc[6] = fmaf(m2, a3[0], acc[6]); acc[7] = fmaf(m2, a3[1], acc[7]);
        }
        {
            auto a0 = __builtin_amdgcn_cvt_pk_f32_fp8((int)v3.x, false);
            auto a1 = __builtin_amdgcn_cvt_pk_f32_fp8((int)v3.x, true);
            auto a2 = __builtin_amdgcn_cvt_pk_f32_fp8((int)v3.y, false);
            auto a3 = __builtin_amdgcn_cvt_pk_f32_fp8((int)v3.y, true);
            acc[0] = fmaf(m3, a0[0], acc[0]); acc[1] = fmaf(m3, a0[1], acc[1]);
            acc[2] = fmaf(m3, a1[0], acc[2]); acc[3] = fmaf(m3, a1[1], acc[3]);
            acc[4] = fmaf(m3, a2[0], acc[4]); acc[5] = fmaf(m3, a2[1], acc[5]);
            acc[6] = fmaf(m3, a3[0], acc[6]); acc[7] = fmaf(m3, a3[1], acc[7]);
        }
    }
#pragma unroll
    for (int t = 0; t < 8; ++t) {
        acc[t] += __shfl_xor(acc[t], 16);
        acc[t] += __shfl_xor(acc[t], 32);
    }
    if (quarter == 0) {
        auto q0 = __builtin_amdgcn_cvt_pk_f32_fp8((int)hw.x, false);
        auto q1 = __builtin_amdgcn_cvt_pk_f32_fp8((int)hw.x, true);
        auto q2 = __builtin_amdgcn_cvt_pk_f32_fp8((int)hw.y, false);
        auto q3 = __builtin_amdgcn_cvt_pk_f32_fp8((int)hw.y, true);
        float hvf[8] = {q0[0], q0[1], q1[0], q1[1], q2[0], q2[1], q3[0], q3[1]};
        float4 b0 = *(const float4*)&bias[c];
        float4 b1 = *(const float4*)&bias[c + 4];
        float bv[8] = {b0.x, b0.y, b0.z, b0.w, b1.x, b1.y, b1.z, b1.w};
        u16x8 o;
#pragma unroll
        for (int t = 0; t < 8; ++t)
            o[t] = f2b(fmaxf(dn * (acc[t] + hvf[t]) + bv[t], 0.f));
        __builtin_nontemporal_store(o, (u16x8*)&xout[(size_t)node * 128 + c]);
    }
}

// ============================= pooling (batch is sorted; x is bf16, fp32 accumulate) =============================
__global__ __launch_bounds__(128) void pool2_kernel(const u16* __restrict__ x_sc,
                                                    const u16* __restrict__ x_fc,
                                                    const int* __restrict__ batch,
                                                    float* __restrict__ g_sc,
                                                    float* __restrict__ g_fc) {
    int b = blockIdx.x;
    const u16* x = (b >= PB) ? x_fc : x_sc;
    float* g     = (b >= PB) ? g_fc : g_sc;
    int blk = (b >= PB) ? b - PB : b;
    int c = threadIdx.x;
    int start = blk * 64;
    if (start >= N_NODES) return;
    int endn = min(start + 64, N_NODES);
    float acc = 0.f;
    int cur = batch[start];
    for (int i = start; i < endn; ++i) {
        int bb = batch[i];
        if (bb != cur) {
            atomicAdd(&g[(size_t)cur * 128 + c], acc);
            acc = 0.f;
            cur = bb;
        }
        acc += b2f(x[(size_t)i * 128 + c]);
    }
    atomicAdd(&g[(size_t)cur * 128 + c], acc);
}

// ============================= row L2-normalize =============================
__global__ __launch_bounds__(64) void normalize_kernel(const float* __restrict__ g_sc,
                                                       const float* __restrict__ g_fc,
                                                       float* __restrict__ n_sc,
                                                       float* __restrict__ n_fc) {
    int r = blockIdx.x & 255;
    const float* g = (blockIdx.x < 256) ? g_sc : g_fc;
    float* o = (blockIdx.x < 256) ? n_sc : n_fc;
    int c = threadIdx.x;
    float v0 = g[r * 128 + c], v1 = g[r * 128 + c + 64];
    float ss = v0 * v0 + v1 * v1;
#pragma unroll
    for (int off = 32; off; off >>= 1) ss += __shfl_xor(ss, off);
    float inv = 1.0f / fmaxf(sqrtf(ss), 1e-12f);
    o[r * 128 + c] = v0 * inv;
    o[r * 128 + c + 64] = v1 * inv;
}

// ============================= classifier head =============================
__global__ __launch_bounds__(128) void head_kernel(const float* __restrict__ g_sc,
                                                   const float* __restrict__ g_fc,
                                                   const float* __restrict__ W1,
                                                   const float* __restrict__ b1,
                                                   const float* __restrict__ W2,
                                                   const float* __restrict__ b2,
                                                   float* __restrict__ out) {
    __shared__ float cat[256];
    __shared__ float red[4];
    int i = blockIdx.x, c = threadIdx.x;
    cat[c] = g_sc[i * 128 + c];
    cat[128 + c] = g_fc[i * 128 + c];
    __syncthreads();
    float acc = b1[c];
    for (int k = 0; k < 256; ++k) acc += cat[k] * W1[k * 128 + c];
    float z = fmaxf(acc, 0.f);
    float l0 = z * W2[c * 2 + 0];
    float l1 = z * W2[c * 2 + 1];
#pragma unroll
    for (int off = 32; off; off >>= 1) {
        l0 += __shfl_xor(l0, off);
        l1 += __shfl_xor(l1, off);
    }
    if ((c & 63) == 0) {
        red[(c >> 6) * 2 + 0] = l0;
        red[(c >> 6) * 2 + 1] = l1;
    }
    __syncthreads();
    if (c == 0) {
        float L0 = red[0] + red[2] + b2[0];
        float L1 = red[1] + red[3] + b2[1];
        float m = fmaxf(L0, L1);
        float lse = m + logf(expf(L0 - m) + expf(L1 - m));
        out[i * 2 + 0] = L0 - lse;
        out[i * 2 + 1] = L1 - lse;
    }
}

// ============================= contrastive loss =============================
__global__ __launch_bounds__(256) void contrast_kernel(const float* __restrict__ n_sc,
                                                       const float* __restrict__ n_fc,
                                                       float* __restrict__ loss_acc) {
    __shared__ float arow[128];
    __shared__ float redm[4];
    __shared__ float reds[4];
    __shared__ float diag_s;
    int b = blockIdx.x;
    int i = b & 255;
    bool which = b >= 256;
    const float* A  = which ? n_fc : n_sc;
    const float* B1 = which ? n_sc : n_fc;
    const float* B2 = which ? n_fc : n_sc;
    int j = threadIdx.x;
    if (j < 128) arow[j] = A[i * 128 + j];
    __syncthreads();
    float d1 = 0.f, d2 = 0.f;
    for (int k = 0; k < 128; ++k) {
        float a = arow[k];
        d1 += a * B1[(size_t)j * 128 + k];
        d2 += a * B2[(size_t)j * 128 + k];
    }
    const float t = 2.0f;  // 1/TEMPERATURE
    float v1 = t * d1;
    float v2 = (j == i) ? 0.0f : 0.8f * t * d2;
    if (j == i) diag_s = v1;
    float m = fmaxf(v1, v2);
#pragma unroll
    for (int off = 32; off; off >>= 1) m = fmaxf(m, __shfl_xor(m, off));
    if ((j & 63) == 0) redm[j >> 6] = m;
    __syncthreads();
    m = fmaxf(fmaxf(redm[0], redm[1]), fmaxf(redm[2], redm[3]));
    float s = expf(v1 - m) + expf(v2 - m);
#pragma unroll
    for (int off = 32; off; off >>= 1) s += __shfl_xor(s, off);
    if ((j & 63) == 0) reds[j >> 6] = s;
    __syncthreads();
    if (j == 0) {
        float S = reds[0] + reds[1] + reds[2] + reds[3];
        float lse = m + logf(S);
        atomicAdd(loss_acc, lse - diag_s);
    }
}

__global__ void final_add(float* __restrict__ out, const float* __restrict__ loss) {
    int t = threadIdx.x;
    if (t < 512) out[t] += loss[0] * (1.0f / 512.0f);
}

// ============================= launch =============================

extern "C" void kernel_launch(void* const* d_in, const int* in_sizes, int n_in,
                              void* d_out, int out_size, void* d_ws, size_t ws_size,
                              hipStream_t stream) {
    const float* sc_x  = (const float*)d_in[0];
    const float* fc_x  = (const float*)d_in[1];
    const int*   sc_ei = (const int*)d_in[2];
    const int*   fc_ei = (const int*)d_in[3];
    const int*   batch = (const int*)d_in[4];
    const float* sc_W  = (const float*)d_in[5];
    const float* sc_b  = (const float*)d_in[6];
    const float* fc_W  = (const float*)d_in[7];
    const float* fc_b  = (const float*)d_in[8];
    const float* fc1_W = (const float*)d_in[9];
    const float* fc1_b = (const float*)d_in[10];
    const float* fc2_W = (const float*)d_in[11];
    const float* fc2_b = (const float*)d_in[12];
    float* out = (float*)d_out;

    const size_t NF = (size_t)N_NODES * HID;     // 12.8M elements
    const size_t TMPSZ = (size_t)NBUCK * BCAP;   // arena records per branch

    float* ws = (float*)d_ws;
    float* dis_sc = ws;                // N f32 (gemm epilogue float4 reads padded by dis_fc)
    float* dis_fc = dis_sc + N_NODES;  // N f32 (padded by g arrays after)
    float* g_sc  = dis_fc + N_NODES;   // g_sc,g_fc contiguous for one memset
    float* g_fc  = g_sc + NGRAPH * HID;
    float* n_sc  = g_fc + NGRAPH * HID;
    float* n_fc  = n_sc + NGRAPH * HID;
    float* lossp = n_fc + NGRAPH * HID;  // 1 (+pad)
    u16* xf_sc   = (u16*)(lossp + 4);    // NF bf16 (final x for pooling)
    u16* xf_fc   = xf_sc + NF;
    u8* h8p_sc   = (u8*)(xf_fc + NF);    // NF fp8 (h ping)
    u8* h8p_fc   = h8p_sc + NF;
    u8* h8q_sc   = h8p_fc + NF;          // NF fp8 (h pong)
    u8* h8q_fc   = h8q_sc + NF;
    u16* Wtb     = (u16*)(h8q_fc + NF);  // 6*16384 bf16 (transposed weights)
    int* srcs_sc   = (int*)(Wtb + 6 * 16384);  // E
    int* srcs_fc   = srcs_sc + N_EDGES;
    u32* tmp_sc    = (u32*)(srcs_fc + N_EDGES);  // NBUCK*BCAP arena records
    u32* tmp_fc    = tmp_sc + TMPSZ;
    int* off_sc    = (int*)(tmp_fc + TMPSZ);     // N+1
    int* off_fc    = off_sc + (N_NODES + 1);
    int* bcur      = off_fc + (N_NODES + 1);     // 2*NBUCK
    int* bktoff    = bcur + 2 * NBUCK;           // 2*(NBUCK+1)
    (void)ws_size; (void)n_in; (void)in_sizes; (void)out_size;

    // ---- CSR build (single edge pass into arenas) ----
    bcur_init_kernel<<<1, 512, 0, stream>>>(bcur);
    buildA_kernel<<<2 * ABLK, 256, 0, stream>>>(sc_ei, fc_ei, bcur, tmp_sc, tmp_fc);
    arena_scan_kernel<<<1, 256, 0, stream>>>(bcur, bktoff);
    bucket_fin_kernel<<<2 * NBUCK, 256, 0, stream>>>(tmp_sc, tmp_fc, bcur, bktoff,
                                                     off_sc, off_fc, dis_sc, dis_fc,
                                                     srcs_sc, srcs_fc);
    convert_w_kernel<<<(6 * 16384 + 255) / 256, 256, 0, stream>>>(sc_W, fc_W, Wtb);

    // ---- layer pipeline: gemm(l0) -> fgg(l0) -> fgg(l1) -> gather(l2), dual-branch ----
    // h stored fp8 ping-pong: h8p (h0) -> h8q (h1) -> h8p (h2) -> xf bf16 (pooled)
    gemm2_kernel<<<2 * GB, 256, 0, stream>>>(sc_x, fc_x, 1, Wtb, 0,
                                             dis_sc, dis_fc, h8p_sc, h8p_fc);
    fgg_kernel<<<2 * FGG_NB, 256, 0, stream>>>(
        h8p_sc, h8p_fc, srcs_sc, srcs_fc, off_sc, off_fc, dis_sc, dis_fc,
        sc_b, fc_b, Wtb, 1, h8q_sc, h8q_fc);
    fgg_kernel<<<2 * FGG_NB, 256, 0, stream>>>(
        h8q_sc, h8q_fc, srcs_sc, srcs_fc, off_sc, off_fc, dis_sc, dis_fc,
        sc_b + HID, fc_b + HID, Wtb, 2, h8p_sc, h8p_fc);
    gather2_kernel<<<2 * GAT_NB, 256, 0, stream>>>(
        h8p_sc, h8p_fc, srcs_sc, srcs_fc, off_sc, off_fc,
        dis_sc, dis_fc, sc_b + 2 * HID, fc_b + 2 * HID, xf_sc, xf_fc);

    // ---- pooling ----
    hipMemsetAsync(g_sc, 0, 2 * NGRAPH * HID * sizeof(float), stream);
    pool2_kernel<<<2 * PB, 128, 0, stream>>>(xf_sc, xf_fc, batch, g_sc, g_fc);

    // ---- head + contrastive ----
    normalize_kernel<<<512, 64, 0, stream>>>(g_sc, g_fc, n_sc, n_fc);
    head_kernel<<<NGRAPH, 128, 0, stream>>>(g_sc, g_fc, fc1_W, fc1_b, fc2_W, fc2_b, out);
    hipMemsetAsync(lossp, 0, sizeof(float), stream);
    contrast_kernel<<<512, 256, 0, stream>>>(n_sc, n_fc, lossp);
    final_add<<<1, 512, 0, stream>>>(out, lossp);
}